// Round 2
// baseline (568.194 us; speedup 1.0000x reference)
//
#include <hip/hip_runtime.h>

#define EMB 768
#define NH 12
#define HD 64
#define BB 32
#define NN 1024

typedef _Float16 h8 __attribute__((ext_vector_type(8)));
typedef _Float16 h4 __attribute__((ext_vector_type(4)));
typedef float f4 __attribute__((ext_vector_type(4)));

static __device__ __forceinline__ f4 mfma16(h8 a, h8 b, f4 c) {
  return __builtin_amdgcn_mfma_f32_16x16x32_f16(a, b, c, 0, 0, 0);
}

// ---------------- X f32 -> f16 ----------------
__global__ __launch_bounds__(256) void k_cvt(const float* __restrict__ X,
                                             _Float16* __restrict__ Xh, int n4) {
  int i = blockIdx.x * 256 + threadIdx.x;
  if (i >= n4) return;
  float4 v = ((const float4*)X)[i];
  h4 o = {(_Float16)v.x, (_Float16)v.y, (_Float16)v.z, (_Float16)v.w};
  ((h4*)Xh)[i] = o;
}

// ---------------- W (768x768 f32) -> W^T f16, all three ----------------
__global__ __launch_bounds__(256) void k_wt(const float* __restrict__ W0,
                                            const float* __restrict__ W1,
                                            const float* __restrict__ W2,
                                            _Float16* __restrict__ Wt) {
  const float* W = blockIdx.z == 0 ? W0 : (blockIdx.z == 1 ? W1 : W2);
  _Float16* dst = Wt + (size_t)blockIdx.z * EMB * EMB;
  __shared__ float tile[64][65];
  const int t = threadIdx.x;
  const int r0 = blockIdx.y * 64, c0 = blockIdx.x * 64;
  const int r = t >> 4, c4 = (t & 15) * 4;
#pragma unroll
  for (int i = 0; i < 4; ++i) {
    const float4 v = *(const float4*)&W[(size_t)(r0 + r + 16 * i) * EMB + c0 + c4];
    tile[r + 16 * i][c4 + 0] = v.x; tile[r + 16 * i][c4 + 1] = v.y;
    tile[r + 16 * i][c4 + 2] = v.z; tile[r + 16 * i][c4 + 3] = v.w;
  }
  __syncthreads();
  const int cc = t >> 2, rr = (t & 3) * 16;
#pragma unroll
  for (int half = 0; half < 2; ++half) {
    h8 o;
#pragma unroll
    for (int j = 0; j < 8; ++j) o[j] = (_Float16)tile[rr + half * 8 + j][cc];
    *(h8*)&dst[(size_t)(c0 + cc) * EMB + r0 + rr + half * 8] = o;
  }
}

// ---------------- projection GEMM: Out[b*12+h][tok][e] = (Xh @ W + bias) * scale ----------------
__global__ __launch_bounds__(256) void k_proj(const _Float16* __restrict__ Xh,
                                              const _Float16* __restrict__ Wt,
                                              const float* __restrict__ bias,
                                              _Float16* __restrict__ Out, float scale) {
  __shared__ _Float16 As[128][40];  // [m][k], pad->2-way max
  __shared__ _Float16 Bs[128][40];  // [n][k] (Wt layout)
  const int t = threadIdx.x;
  const int w = t >> 6, l = t & 63;
  const int wm = w >> 1, wn = w & 1;
  const int m0 = blockIdx.x * 128, n0 = blockIdx.y * 128;
  f4 acc[4][4];
#pragma unroll
  for (int mf = 0; mf < 4; ++mf)
#pragma unroll
    for (int nf = 0; nf < 4; ++nf) acc[mf][nf] = f4{0.f, 0.f, 0.f, 0.f};

  const int srow = t >> 2, sc = (t & 3) * 8;
  for (int k0 = 0; k0 < EMB; k0 += 32) {
#pragma unroll
    for (int i = 0; i < 2; ++i) {
      *(h8*)&As[srow + 64 * i][sc] = *(const h8*)&Xh[(size_t)(m0 + srow + 64 * i) * EMB + k0 + sc];
      *(h8*)&Bs[srow + 64 * i][sc] = *(const h8*)&Wt[(size_t)(n0 + srow + 64 * i) * EMB + k0 + sc];
    }
    __syncthreads();
    h8 af[4], bf[4];
#pragma unroll
    for (int mf = 0; mf < 4; ++mf) af[mf] = *(const h8*)&As[wm * 64 + mf * 16 + (l & 15)][(l >> 4) * 8];
#pragma unroll
    for (int nf = 0; nf < 4; ++nf) bf[nf] = *(const h8*)&Bs[wn * 64 + nf * 16 + (l & 15)][(l >> 4) * 8];
#pragma unroll
    for (int mf = 0; mf < 4; ++mf)
#pragma unroll
      for (int nf = 0; nf < 4; ++nf) acc[mf][nf] = mfma16(af[mf], bf[nf], acc[mf][nf]);
    __syncthreads();
  }
  // epilogue: C/D layout col=lane&15, row=(lane>>4)*4+reg  [m89/m91]
#pragma unroll
  for (int nf = 0; nf < 4; ++nf) {
    const int C = n0 + wn * 64 + nf * 16 + (l & 15);
    const float bvv = bias[C];
    const int h = C >> 6, e = C & 63;
#pragma unroll
    for (int mf = 0; mf < 4; ++mf) {
#pragma unroll
      for (int r = 0; r < 4; ++r) {
        const int R = m0 + wm * 64 + mf * 16 + (l >> 4) * 4 + r;
        const int b = R >> 10, tok = R & 1023;
        Out[((size_t)(b * NH + h) * NN + tok) * HD + e] = (_Float16)((acc[mf][nf][r] + bvv) * scale);
      }
    }
  }
}

// ---------------- V [bh][j][e] -> Vt [bh][e][j] ----------------
__global__ __launch_bounds__(256) void k_vt(const _Float16* __restrict__ Vtmp,
                                            _Float16* __restrict__ Vt) {
  const int bh = blockIdx.y, j0 = blockIdx.x * 64;
  __shared__ _Float16 tile[64][72];
  const _Float16* src = Vtmp + (size_t)bh * NN * HD;
  _Float16* dst = Vt + (size_t)bh * HD * NN;
  const int t = threadIdx.x;
  const int jr = t >> 3, e8 = (t & 7) * 8;
#pragma unroll
  for (int i = 0; i < 2; ++i)
    *(h8*)&tile[jr + 32 * i][e8] = *(const h8*)&src[(size_t)(j0 + jr + 32 * i) * HD + e8];
  __syncthreads();
  const int er = t >> 3, j8 = (t & 7) * 8;
#pragma unroll
  for (int i = 0; i < 2; ++i) {
    h8 o;
#pragma unroll
    for (int j = 0; j < 8; ++j) o[j] = tile[j8 + j][er + 32 * i];
    *(h8*)&dst[(size_t)(er + 32 * i) * NN + j0 + j8] = o;
  }
}

// ---------------- column stats: m[j] = max_i S, l[j] = sum_i exp(S-m) ----------------
__global__ __launch_bounds__(256) void k_stats(const _Float16* __restrict__ Q,
                                               const _Float16* __restrict__ K,
                                               float* __restrict__ Mg, float* __restrict__ Lg) {
  const int bh = blockIdx.y, j0 = blockIdx.x * 128;
  __shared__ _Float16 Ks[128][72];
  __shared__ _Float16 Qs[128][72];
  __shared__ float Mj[128], Lj[128];
  __shared__ float redm[2][128], reds[2][128];
  const _Float16* Qb = Q + (size_t)bh * NN * HD;
  const _Float16* Kb = K + (size_t)bh * NN * HD;
  const int t = threadIdx.x, w = t >> 6, l = t & 63;
  const int wi = w >> 1, wj = w & 1;
  const int lr = t >> 3, c8 = (t & 7) * 8;
#pragma unroll
  for (int i = 0; i < 4; ++i)
    *(h8*)&Ks[lr + 32 * i][c8] = *(const h8*)&Kb[(size_t)(j0 + lr + 32 * i) * HD + c8];
  if (t < 128) { Mj[t] = -1e30f; Lj[t] = 0.f; }
  __syncthreads();

  for (int i0 = 0; i0 < NN; i0 += 128) {
#pragma unroll
    for (int i = 0; i < 4; ++i)
      *(h8*)&Qs[lr + 32 * i][c8] = *(const h8*)&Qb[(size_t)(i0 + lr + 32 * i) * HD + c8];
    __syncthreads();
    f4 s[4][4];
#pragma unroll
    for (int mf = 0; mf < 4; ++mf)
#pragma unroll
      for (int nf = 0; nf < 4; ++nf) s[mf][nf] = f4{0.f, 0.f, 0.f, 0.f};
#pragma unroll
    for (int ks = 0; ks < 2; ++ks) {
      h8 af[4], bf[4];
#pragma unroll
      for (int mf = 0; mf < 4; ++mf) af[mf] = *(const h8*)&Qs[wi * 64 + mf * 16 + (l & 15)][ks * 32 + (l >> 4) * 8];
#pragma unroll
      for (int nf = 0; nf < 4; ++nf) bf[nf] = *(const h8*)&Ks[wj * 64 + nf * 16 + (l & 15)][ks * 32 + (l >> 4) * 8];
#pragma unroll
      for (int mf = 0; mf < 4; ++mf)
#pragma unroll
        for (int nf = 0; nf < 4; ++nf) s[mf][nf] = mfma16(af[mf], bf[nf], s[mf][nf]);
    }
    // per-wave column (i-axis) reduce: rows live in regs + lane bits 4,5
#pragma unroll
    for (int nf = 0; nf < 4; ++nf) {
      float cm = -1e30f;
#pragma unroll
      for (int mf = 0; mf < 4; ++mf)
#pragma unroll
        for (int r = 0; r < 4; ++r) cm = fmaxf(cm, s[mf][nf][r]);
      cm = fmaxf(cm, __shfl_xor(cm, 16));
      cm = fmaxf(cm, __shfl_xor(cm, 32));
      float cs = 0.f;
#pragma unroll
      for (int mf = 0; mf < 4; ++mf)
#pragma unroll
        for (int r = 0; r < 4; ++r) cs += __expf(s[mf][nf][r] - cm);
      cs += __shfl_xor(cs, 16);
      cs += __shfl_xor(cs, 32);
      if (l < 16) {
        redm[wi][wj * 64 + nf * 16 + l] = cm;
        reds[wi][wj * 64 + nf * 16 + l] = cs;
      }
    }
    __syncthreads();
    if (t < 128) {
      const float mo = Mj[t], p0 = redm[0][t], p1 = redm[1][t];
      const float nm = fmaxf(mo, fmaxf(p0, p1));
      Lj[t] = Lj[t] * __expf(mo - nm) + reds[0][t] * __expf(p0 - nm) + reds[1][t] * __expf(p1 - nm);
      Mj[t] = nm;
    }
    __syncthreads();
  }
  if (t < 128) {
    Mg[(size_t)bh * NN + j0 + t] = Mj[t];
    Lg[(size_t)bh * NN + j0 + t] = Lj[t];
  }
}

// ---------------- output: out = (exp(S - m[j]) / l[j]) @ V ----------------
__global__ __launch_bounds__(256) void k_out(const _Float16* __restrict__ Q,
                                             const _Float16* __restrict__ K,
                                             const _Float16* __restrict__ Vt,
                                             const float* __restrict__ Mg,
                                             const float* __restrict__ Lg,
                                             float* __restrict__ Out) {
  const int bh = blockIdx.y, i0 = blockIdx.x * 128;
  const int b = bh / NH, h = bh % NH;
  __shared__ _Float16 Ks[128][72];
  __shared__ _Float16 Vts[64][136];   // [e][j]
  __shared__ _Float16 Ps[128][136];   // [i][j]
  __shared__ float Mjl[128], Linv[128];
  const _Float16* Qb = Q + (size_t)bh * NN * HD;
  const _Float16* Kb = K + (size_t)bh * NN * HD;
  const _Float16* Vb = Vt + (size_t)bh * HD * NN;
  const int t = threadIdx.x, w = t >> 6, l = t & 63;
  const int wi = w >> 1, wj = w & 1;

  // Q fragments held in registers (wave's 64 rows, full e=64)
  h8 aq[4][2];
#pragma unroll
  for (int mf = 0; mf < 4; ++mf)
#pragma unroll
    for (int ks = 0; ks < 2; ++ks)
      aq[mf][ks] = *(const h8*)&Qb[(size_t)(i0 + wi * 64 + mf * 16 + (l & 15)) * HD + ks * 32 + (l >> 4) * 8];

  f4 oacc[4][2];
#pragma unroll
  for (int mf = 0; mf < 4; ++mf)
#pragma unroll
    for (int nf = 0; nf < 2; ++nf) oacc[mf][nf] = f4{0.f, 0.f, 0.f, 0.f};

  const int lr = t >> 3, c8 = (t & 7) * 8;   // K staging
  const int er = t >> 4, j8 = (t & 15) * 8;  // Vt staging

  for (int jt = 0; jt < 8; ++jt) {
    const int j0 = jt * 128;
    __syncthreads();  // prev PV (reads Ps,Vts) done before restage
#pragma unroll
    for (int i = 0; i < 4; ++i)
      *(h8*)&Ks[lr + 32 * i][c8] = *(const h8*)&Kb[(size_t)(j0 + lr + 32 * i) * HD + c8];
#pragma unroll
    for (int i = 0; i < 4; ++i)
      *(h8*)&Vts[er + 16 * i][j8] = *(const h8*)&Vb[(size_t)(er + 16 * i) * NN + j0 + j8];
    if (t < 128) {
      Mjl[t] = Mg[(size_t)bh * NN + j0 + t];
      Linv[t] = 1.f / Lg[(size_t)bh * NN + j0 + t];
    }
    __syncthreads();
    // S quadrant
    f4 s[4][4];
#pragma unroll
    for (int mf = 0; mf < 4; ++mf)
#pragma unroll
      for (int nf = 0; nf < 4; ++nf) s[mf][nf] = f4{0.f, 0.f, 0.f, 0.f};
#pragma unroll
    for (int ks = 0; ks < 2; ++ks) {
      h8 bf[4];
#pragma unroll
      for (int nf = 0; nf < 4; ++nf) bf[nf] = *(const h8*)&Ks[wj * 64 + nf * 16 + (l & 15)][ks * 32 + (l >> 4) * 8];
#pragma unroll
      for (int mf = 0; mf < 4; ++mf)
#pragma unroll
        for (int nf = 0; nf < 4; ++nf) s[mf][nf] = mfma16(aq[mf][ks], bf[nf], s[mf][nf]);
    }
    // P = exp(S - m[j]) * (1/l[j]) -> LDS (f16, values <= 1)
#pragma unroll
    for (int nf = 0; nf < 4; ++nf) {
      const int jl = wj * 64 + nf * 16 + (l & 15);
      const float mj = Mjl[jl], li = Linv[jl];
#pragma unroll
      for (int mf = 0; mf < 4; ++mf) {
        const int irow = wi * 64 + mf * 16 + (l >> 4) * 4;
#pragma unroll
        for (int r = 0; r < 4; ++r)
          Ps[irow + r][jl] = (_Float16)(__expf(s[mf][nf][r] - mj) * li);
      }
    }
    __syncthreads();
    // PV: out[128 x 64] over this j-tile; wave -> rows wi*64, cols wj*32
#pragma unroll
    for (int ks = 0; ks < 4; ++ks) {
      h8 ap[4], bv2[2];
#pragma unroll
      for (int mf = 0; mf < 4; ++mf) ap[mf] = *(const h8*)&Ps[wi * 64 + mf * 16 + (l & 15)][ks * 32 + (l >> 4) * 8];
#pragma unroll
      for (int nf = 0; nf < 2; ++nf) bv2[nf] = *(const h8*)&Vts[wj * 32 + nf * 16 + (l & 15)][ks * 32 + (l >> 4) * 8];
#pragma unroll
      for (int mf = 0; mf < 4; ++mf)
#pragma unroll
        for (int nf = 0; nf < 2; ++nf) oacc[mf][nf] = mfma16(ap[mf], bv2[nf], oacc[mf][nf]);
    }
  }
  // write f32 output [b][i][h*64+e]
#pragma unroll
  for (int nf = 0; nf < 2; ++nf) {
    const int e = wj * 32 + nf * 16 + (l & 15);
#pragma unroll
    for (int mf = 0; mf < 4; ++mf) {
#pragma unroll
      for (int r = 0; r < 4; ++r) {
        const int irow = i0 + wi * 64 + mf * 16 + (l >> 4) * 4 + r;
        Out[((size_t)b * NN + irow) * EMB + h * HD + e] = oacc[mf][nf][r];
      }
    }
  }
}

extern "C" void kernel_launch(void* const* d_in, const int* in_sizes, int n_in,
                              void* d_out, int out_size, void* d_ws, size_t ws_size,
                              hipStream_t stream) {
  const float* X  = (const float*)d_in[0];
  const float* Wq = (const float*)d_in[1];
  const float* bq = (const float*)d_in[2];
  const float* Wk = (const float*)d_in[3];
  const float* bk = (const float*)d_in[4];
  const float* Wv = (const float*)d_in[5];
  const float* bv = (const float*)d_in[6];

  // workspace layout (needs ~157.7 MB)
  char* ws = (char*)d_ws;
  _Float16* Qw = (_Float16*)(ws);                  // 50,331,648 B
  _Float16* Kw = (_Float16*)(ws + 50331648);       // 50,331,648 B
  _Float16* Vt = (_Float16*)(ws + 100663296);      // 50,331,648 B
  _Float16* Wt = (_Float16*)(ws + 150994944);      // 3 * 1,179,648 B
  float* Mg    = (float*)(ws + 154533888);         // 1,572,864 B
  float* Lg    = (float*)(ws + 156106752);         // 1,572,864 B

  // transients inside d_out (overwritten by final f32 result at the end)
  _Float16* Xh   = (_Float16*)d_out;                        // 50,331,648 B
  _Float16* Vtmp = (_Float16*)((char*)d_out + 50331648);    // 50,331,648 B
  float* Out = (float*)d_out;

  k_cvt<<<dim3(6291456 / 256), 256, 0, stream>>>(X, Xh, 6291456);
  k_wt<<<dim3(12, 12, 3), 256, 0, stream>>>(Wq, Wk, Wv, Wt);
  k_proj<<<dim3(256, 6), 256, 0, stream>>>(Xh, Wt,           bq, Qw,   0.2886751345948129f);
  k_proj<<<dim3(256, 6), 256, 0, stream>>>(Xh, Wt + 589824,  bk, Kw,   1.0f);
  k_proj<<<dim3(256, 6), 256, 0, stream>>>(Xh, Wt + 1179648, bv, Vtmp, 1.0f);
  k_vt<<<dim3(16, 384), 256, 0, stream>>>(Vtmp, Vt);
  k_stats<<<dim3(8, 384), 256, 0, stream>>>(Qw, Kw, Mg, Lg);
  k_out<<<dim3(8, 384), 256, 0, stream>>>(Qw, Kw, Vt, Mg, Lg, Out);
}

// Round 3
// 565.081 us; speedup vs baseline: 1.0055x; 1.0055x over previous
//
#include <hip/hip_runtime.h>

#define EMB 768
#define NH 12
#define HD 64
#define BB 32
#define NN 1024

typedef _Float16 h8 __attribute__((ext_vector_type(8)));
typedef _Float16 h4 __attribute__((ext_vector_type(4)));
typedef float f4 __attribute__((ext_vector_type(4)));

static __device__ __forceinline__ f4 mfma16(h8 a, h8 b, f4 c) {
  return __builtin_amdgcn_mfma_f32_16x16x32_f16(a, b, c, 0, 0, 0);
}

// ---------------- X f32 -> f16 ----------------
__global__ __launch_bounds__(256) void k_cvt(const float* __restrict__ X,
                                             _Float16* __restrict__ Xh, int n4) {
  int i = blockIdx.x * 256 + threadIdx.x;
  if (i >= n4) return;
  float4 v = ((const float4*)X)[i];
  h4 o = {(_Float16)v.x, (_Float16)v.y, (_Float16)v.z, (_Float16)v.w};
  ((h4*)Xh)[i] = o;
}

// ---------------- W (768x768 f32) -> W^T f16, all three ----------------
__global__ __launch_bounds__(256) void k_wt(const float* __restrict__ W0,
                                            const float* __restrict__ W1,
                                            const float* __restrict__ W2,
                                            _Float16* __restrict__ Wt) {
  const float* W = blockIdx.z == 0 ? W0 : (blockIdx.z == 1 ? W1 : W2);
  _Float16* dst = Wt + (size_t)blockIdx.z * EMB * EMB;
  __shared__ float tile[64][65];
  const int t = threadIdx.x;
  const int r0 = blockIdx.y * 64, c0 = blockIdx.x * 64;
  const int r = t >> 4, c4 = (t & 15) * 4;
#pragma unroll
  for (int i = 0; i < 4; ++i) {
    const float4 v = *(const float4*)&W[(size_t)(r0 + r + 16 * i) * EMB + c0 + c4];
    tile[r + 16 * i][c4 + 0] = v.x; tile[r + 16 * i][c4 + 1] = v.y;
    tile[r + 16 * i][c4 + 2] = v.z; tile[r + 16 * i][c4 + 3] = v.w;
  }
  __syncthreads();
  const int cc = t >> 2, rr = (t & 3) * 16;
#pragma unroll
  for (int half = 0; half < 2; ++half) {
    h8 o;
#pragma unroll
    for (int j = 0; j < 8; ++j) o[j] = (_Float16)tile[rr + half * 8 + j][cc];
    *(h8*)&dst[(size_t)(c0 + cc) * EMB + r0 + rr + half * 8] = o;
  }
}

// ---------------- projection GEMM: Out[b*12+h][tok][e] = (Xh @ W + bias) * scale ----------------
__global__ __launch_bounds__(256) void k_proj(const _Float16* __restrict__ Xh,
                                              const _Float16* __restrict__ Wt,
                                              const float* __restrict__ bias,
                                              _Float16* __restrict__ Out, float scale) {
  __shared__ _Float16 As[128][40];  // [m][k]
  __shared__ _Float16 Bs[128][40];  // [n][k] (Wt layout)
  const int t = threadIdx.x;
  const int w = t >> 6, l = t & 63;
  const int wm = w >> 1, wn = w & 1;
  const int m0 = blockIdx.x * 128, n0 = blockIdx.y * 128;
  f4 acc[4][4];
#pragma unroll
  for (int mf = 0; mf < 4; ++mf)
#pragma unroll
    for (int nf = 0; nf < 4; ++nf) acc[mf][nf] = f4{0.f, 0.f, 0.f, 0.f};

  const int srow = t >> 2, sc = (t & 3) * 8;
  for (int k0 = 0; k0 < EMB; k0 += 32) {
#pragma unroll
    for (int i = 0; i < 2; ++i) {
      *(h8*)&As[srow + 64 * i][sc] = *(const h8*)&Xh[(size_t)(m0 + srow + 64 * i) * EMB + k0 + sc];
      *(h8*)&Bs[srow + 64 * i][sc] = *(const h8*)&Wt[(size_t)(n0 + srow + 64 * i) * EMB + k0 + sc];
    }
    __syncthreads();
    h8 af[4], bf[4];
#pragma unroll
    for (int mf = 0; mf < 4; ++mf) af[mf] = *(const h8*)&As[wm * 64 + mf * 16 + (l & 15)][(l >> 4) * 8];
#pragma unroll
    for (int nf = 0; nf < 4; ++nf) bf[nf] = *(const h8*)&Bs[wn * 64 + nf * 16 + (l & 15)][(l >> 4) * 8];
#pragma unroll
    for (int mf = 0; mf < 4; ++mf)
#pragma unroll
      for (int nf = 0; nf < 4; ++nf) acc[mf][nf] = mfma16(af[mf], bf[nf], acc[mf][nf]);
    __syncthreads();
  }
#pragma unroll
  for (int nf = 0; nf < 4; ++nf) {
    const int C = n0 + wn * 64 + nf * 16 + (l & 15);
    const float bvv = bias[C];
    const int h = C >> 6, e = C & 63;
#pragma unroll
    for (int mf = 0; mf < 4; ++mf) {
#pragma unroll
      for (int r = 0; r < 4; ++r) {
        const int R = m0 + wm * 64 + mf * 16 + (l >> 4) * 4 + r;
        const int b = R >> 10, tok = R & 1023;
        Out[((size_t)(b * NH + h) * NN + tok) * HD + e] = (_Float16)((acc[mf][nf][r] + bvv) * scale);
      }
    }
  }
}

// ---------------- column stats: Lg'[j] = l_j*exp(m_j - M*_tile), MT[tile] = M* ----------------
__global__ __launch_bounds__(256) void k_stats(const _Float16* __restrict__ Q,
                                               const _Float16* __restrict__ K,
                                               float* __restrict__ Lg, float* __restrict__ MT) {
  const int bh = blockIdx.y, j0 = blockIdx.x * 128;
  __shared__ _Float16 Ks[128][72];
  __shared__ _Float16 Qs[128][72];
  __shared__ float Mj[128], Lj[128];
  __shared__ float redm[2][128], reds[2][128];
  __shared__ float MsSh;
  const _Float16* Qb = Q + (size_t)bh * NN * HD;
  const _Float16* Kb = K + (size_t)bh * NN * HD;
  const int t = threadIdx.x, w = t >> 6, l = t & 63;
  const int wi = w >> 1, wj = w & 1;
  const int lr = t >> 3, c8 = (t & 7) * 8;
#pragma unroll
  for (int i = 0; i < 4; ++i)
    *(h8*)&Ks[lr + 32 * i][c8] = *(const h8*)&Kb[(size_t)(j0 + lr + 32 * i) * HD + c8];
  if (t < 128) { Mj[t] = -1e30f; Lj[t] = 0.f; }
  __syncthreads();

  for (int i0 = 0; i0 < NN; i0 += 128) {
#pragma unroll
    for (int i = 0; i < 4; ++i)
      *(h8*)&Qs[lr + 32 * i][c8] = *(const h8*)&Qb[(size_t)(i0 + lr + 32 * i) * HD + c8];
    __syncthreads();
    f4 s[4][4];
#pragma unroll
    for (int mf = 0; mf < 4; ++mf)
#pragma unroll
      for (int nf = 0; nf < 4; ++nf) s[mf][nf] = f4{0.f, 0.f, 0.f, 0.f};
#pragma unroll
    for (int ks = 0; ks < 2; ++ks) {
      h8 af[4], bf[4];
#pragma unroll
      for (int mf = 0; mf < 4; ++mf) af[mf] = *(const h8*)&Qs[wi * 64 + mf * 16 + (l & 15)][ks * 32 + (l >> 4) * 8];
#pragma unroll
      for (int nf = 0; nf < 4; ++nf) bf[nf] = *(const h8*)&Ks[wj * 64 + nf * 16 + (l & 15)][ks * 32 + (l >> 4) * 8];
#pragma unroll
      for (int mf = 0; mf < 4; ++mf)
#pragma unroll
        for (int nf = 0; nf < 4; ++nf) s[mf][nf] = mfma16(af[mf], bf[nf], s[mf][nf]);
    }
#pragma unroll
    for (int nf = 0; nf < 4; ++nf) {
      float cm = -1e30f;
#pragma unroll
      for (int mf = 0; mf < 4; ++mf)
#pragma unroll
        for (int r = 0; r < 4; ++r) cm = fmaxf(cm, s[mf][nf][r]);
      cm = fmaxf(cm, __shfl_xor(cm, 16));
      cm = fmaxf(cm, __shfl_xor(cm, 32));
      float cs = 0.f;
#pragma unroll
      for (int mf = 0; mf < 4; ++mf)
#pragma unroll
        for (int r = 0; r < 4; ++r) cs += __expf(s[mf][nf][r] - cm);
      cs += __shfl_xor(cs, 16);
      cs += __shfl_xor(cs, 32);
      if (l < 16) {
        redm[wi][wj * 64 + nf * 16 + l] = cm;
        reds[wi][wj * 64 + nf * 16 + l] = cs;
      }
    }
    __syncthreads();
    if (t < 128) {
      const float mo = Mj[t], p0 = redm[0][t], p1 = redm[1][t];
      const float nm = fmaxf(mo, fmaxf(p0, p1));
      Lj[t] = Lj[t] * __expf(mo - nm) + reds[0][t] * __expf(p0 - nm) + reds[1][t] * __expf(p1 - nm);
      Mj[t] = nm;
    }
    __syncthreads();
  }
  // tail: tile max M*, scaled denom
  if (w == 0) {
    float mv = fmaxf(Mj[l], Mj[l + 64]);
#pragma unroll
    for (int d = 32; d; d >>= 1) mv = fmaxf(mv, __shfl_xor(mv, d));
    if (l == 0) { MsSh = mv; MT[bh * 8 + blockIdx.x] = mv; }
  }
  __syncthreads();
  if (t < 128) Lg[(size_t)bh * NN + j0 + t] = Lj[t] * __expf(Mj[t] - MsSh);
}

// ---------------- V [bh][j][e] -> Vt [bh][e][j] scaled by 1/Lg'[j] ----------------
__global__ __launch_bounds__(256) void k_vt(const _Float16* __restrict__ Vtmp,
                                            const float* __restrict__ Lg,
                                            _Float16* __restrict__ Vt) {
  const int bh = blockIdx.y, j0 = blockIdx.x * 64;
  __shared__ _Float16 tile[64][72];
  const _Float16* src = Vtmp + (size_t)bh * NN * HD;
  _Float16* dst = Vt + (size_t)bh * HD * NN;
  const int t = threadIdx.x;
  const int jr = t >> 3, e8 = (t & 7) * 8;
#pragma unroll
  for (int i = 0; i < 2; ++i) {
    const float inv = 1.0f / Lg[(size_t)bh * NN + j0 + jr + 32 * i];
    h8 v = *(const h8*)&src[(size_t)(j0 + jr + 32 * i) * HD + e8];
    h8 o;
#pragma unroll
    for (int j = 0; j < 8; ++j) o[j] = (_Float16)((float)v[j] * inv);
    *(h8*)&tile[jr + 32 * i][e8] = o;
  }
  __syncthreads();
  const int er = t >> 3, j8 = (t & 7) * 8;
#pragma unroll
  for (int i = 0; i < 2; ++i) {
    h8 o;
#pragma unroll
    for (int j = 0; j < 8; ++j) o[j] = tile[j8 + j][er + 32 * i];
    *(h8*)&dst[(size_t)(er + 32 * i) * NN + j0 + j8] = o;
  }
}

// ---------------- output: out = exp(S - M*[tile]) @ V' ----------------
__global__ __launch_bounds__(256) void k_out(const _Float16* __restrict__ Q,
                                             const _Float16* __restrict__ K,
                                             const _Float16* __restrict__ Vt,
                                             const float* __restrict__ MT,
                                             float* __restrict__ Out) {
  const int bh = blockIdx.y, i0 = blockIdx.x * 128;
  const int b = bh / NH, h = bh % NH;
  __shared__ _Float16 Ks[64][72];    // [j][e]
  __shared__ _Float16 Vts[64][72];   // [e][j]
  __shared__ _Float16 Ps[128][72];   // [i][j]
  const _Float16* Qb = Q + (size_t)bh * NN * HD;
  const _Float16* Kb = K + (size_t)bh * NN * HD;
  const _Float16* Vb = Vt + (size_t)bh * HD * NN;
  const int t = threadIdx.x, w = t >> 6, l = t & 63;
  const int wi = w >> 1, wj = w & 1;
  const int p = l & 15, g = l >> 4;

  // Q A-frags in registers: rows i0+wi*64+16mf+p, k = 32ks+8g..
  h8 aq[4][2];
#pragma unroll
  for (int mf = 0; mf < 4; ++mf)
#pragma unroll
    for (int ks = 0; ks < 2; ++ks)
      aq[mf][ks] = *(const h8*)&Qb[(size_t)(i0 + wi * 64 + mf * 16 + p) * HD + ks * 32 + g * 8];

  f4 oacc[4][2];
#pragma unroll
  for (int mf = 0; mf < 4; ++mf)
#pragma unroll
    for (int ef = 0; ef < 2; ++ef) oacc[mf][ef] = f4{0.f, 0.f, 0.f, 0.f};

  const int sr = t >> 3, sc = (t & 7) * 8;

  for (int jt = 0; jt < 16; ++jt) {
    const int j0 = jt * 64;
    const float Mstar = MT[bh * 8 + (jt >> 1)];
    __syncthreads();  // prev PV reads done before restage / Ps rewrite
#pragma unroll
    for (int i = 0; i < 2; ++i) {
      *(h8*)&Ks[sr + 32 * i][sc]  = *(const h8*)&Kb[(size_t)(j0 + sr + 32 * i) * HD + sc];
      *(h8*)&Vts[sr + 32 * i][sc] = *(const h8*)&Vb[(size_t)(sr + 32 * i) * NN + j0 + sc];
    }
    __syncthreads();
    // S quadrant: rows (wi) 64, cols (wj) 32
    f4 s[4][2];
#pragma unroll
    for (int mf = 0; mf < 4; ++mf)
#pragma unroll
      for (int nf = 0; nf < 2; ++nf) s[mf][nf] = f4{0.f, 0.f, 0.f, 0.f};
#pragma unroll
    for (int ks = 0; ks < 2; ++ks) {
      h8 bf[2];
#pragma unroll
      for (int nf = 0; nf < 2; ++nf) bf[nf] = *(const h8*)&Ks[wj * 32 + nf * 16 + p][ks * 32 + g * 8];
#pragma unroll
      for (int mf = 0; mf < 4; ++mf)
#pragma unroll
        for (int nf = 0; nf < 2; ++nf) s[mf][nf] = mfma16(aq[mf][ks], bf[nf], s[mf][nf]);
    }
    // P = exp(S - M*)  (1/l folded into V')
#pragma unroll
    for (int nf = 0; nf < 2; ++nf) {
      const int jl = wj * 32 + nf * 16 + p;
#pragma unroll
      for (int mf = 0; mf < 4; ++mf) {
        const int ir = wi * 64 + mf * 16 + g * 4;
#pragma unroll
        for (int r = 0; r < 4; ++r)
          Ps[ir + r][jl] = (_Float16)__expf(s[mf][nf][r] - Mstar);
      }
    }
    __syncthreads();
    // PV over this j-tile
#pragma unroll
    for (int ks = 0; ks < 2; ++ks) {
      h8 ap[4], bv2[2];
#pragma unroll
      for (int mf = 0; mf < 4; ++mf) ap[mf] = *(const h8*)&Ps[wi * 64 + mf * 16 + p][ks * 32 + g * 8];
#pragma unroll
      for (int ef = 0; ef < 2; ++ef) bv2[ef] = *(const h8*)&Vts[wj * 32 + ef * 16 + p][ks * 32 + g * 8];
#pragma unroll
      for (int mf = 0; mf < 4; ++mf)
#pragma unroll
        for (int ef = 0; ef < 2; ++ef) oacc[mf][ef] = mfma16(ap[mf], bv2[ef], oacc[mf][ef]);
    }
  }
  // write f32 output [b][i][h*64+e]
#pragma unroll
  for (int ef = 0; ef < 2; ++ef) {
    const int e = h * HD + wj * 32 + ef * 16 + p;
#pragma unroll
    for (int mf = 0; mf < 4; ++mf) {
#pragma unroll
      for (int r = 0; r < 4; ++r) {
        const int ir = i0 + wi * 64 + mf * 16 + g * 4 + r;
        Out[((size_t)b * NN + ir) * EMB + e] = oacc[mf][ef][r];
      }
    }
  }
}

extern "C" void kernel_launch(void* const* d_in, const int* in_sizes, int n_in,
                              void* d_out, int out_size, void* d_ws, size_t ws_size,
                              hipStream_t stream) {
  const float* X  = (const float*)d_in[0];
  const float* Wq = (const float*)d_in[1];
  const float* bq = (const float*)d_in[2];
  const float* Wk = (const float*)d_in[3];
  const float* bk = (const float*)d_in[4];
  const float* Wv = (const float*)d_in[5];
  const float* bv = (const float*)d_in[6];

  // workspace layout (~156.1 MB)
  char* ws = (char*)d_ws;
  _Float16* Qw = (_Float16*)(ws);                  // 50,331,648 B
  _Float16* Kw = (_Float16*)(ws + 50331648);       // 50,331,648 B
  _Float16* Vt = (_Float16*)(ws + 100663296);      // 50,331,648 B
  _Float16* Wt = (_Float16*)(ws + 150994944);      // 3 * 1,179,648 B
  float* Lg    = (float*)(ws + 154533888);         // 1,572,864 B
  float* MT    = (float*)(ws + 156106752);         // 12,288 B

  // transients inside d_out (overwritten by final f32 result at the end)
  _Float16* Xh   = (_Float16*)d_out;                        // 50,331,648 B
  _Float16* Vtmp = (_Float16*)((char*)d_out + 50331648);    // 50,331,648 B
  float* Out = (float*)d_out;

  k_cvt<<<dim3(6291456 / 256), 256, 0, stream>>>(X, Xh, 6291456);
  k_wt<<<dim3(12, 12, 3), 256, 0, stream>>>(Wq, Wk, Wv, Wt);
  k_proj<<<dim3(256, 6), 256, 0, stream>>>(Xh, Wt,           bq, Qw,   0.2886751345948129f);
  k_proj<<<dim3(256, 6), 256, 0, stream>>>(Xh, Wt + 589824,  bk, Kw,   1.0f);
  k_proj<<<dim3(256, 6), 256, 0, stream>>>(Xh, Wt + 1179648, bv, Vtmp, 1.0f);
  k_stats<<<dim3(8, 384), 256, 0, stream>>>(Qw, Kw, Lg, MT);
  k_vt<<<dim3(16, 384), 256, 0, stream>>>(Vtmp, Lg, Vt);
  k_out<<<dim3(8, 384), 256, 0, stream>>>(Qw, Kw, Vt, MT, Out);
}

// Round 4
// 530.900 us; speedup vs baseline: 1.0702x; 1.0644x over previous
//
#include <hip/hip_runtime.h>

#define EMB 768
#define NH 12
#define HD 64
#define BB 32
#define NN 1024

typedef _Float16 h8 __attribute__((ext_vector_type(8)));
typedef _Float16 h4 __attribute__((ext_vector_type(4)));
typedef float f4 __attribute__((ext_vector_type(4)));

static __device__ __forceinline__ f4 mfma16(h8 a, h8 b, f4 c) {
  return __builtin_amdgcn_mfma_f32_16x16x32_f16(a, b, c, 0, 0, 0);
}

// ---------------- X f32 -> f16 ----------------
__global__ __launch_bounds__(256) void k_cvt(const float* __restrict__ X,
                                             _Float16* __restrict__ Xh, int n4) {
  int i = blockIdx.x * 256 + threadIdx.x;
  if (i >= n4) return;
  float4 v = ((const float4*)X)[i];
  h4 o = {(_Float16)v.x, (_Float16)v.y, (_Float16)v.z, (_Float16)v.w};
  ((h4*)Xh)[i] = o;
}

// ---------------- W (768x768 f32) -> W^T f16, all three ----------------
__global__ __launch_bounds__(256) void k_wt(const float* __restrict__ W0,
                                            const float* __restrict__ W1,
                                            const float* __restrict__ W2,
                                            _Float16* __restrict__ Wt) {
  const float* W = blockIdx.z == 0 ? W0 : (blockIdx.z == 1 ? W1 : W2);
  _Float16* dst = Wt + (size_t)blockIdx.z * EMB * EMB;
  __shared__ float tile[64][65];
  const int t = threadIdx.x;
  const int r0 = blockIdx.y * 64, c0 = blockIdx.x * 64;
  const int r = t >> 4, c4 = (t & 15) * 4;
#pragma unroll
  for (int i = 0; i < 4; ++i) {
    const float4 v = *(const float4*)&W[(size_t)(r0 + r + 16 * i) * EMB + c0 + c4];
    tile[r + 16 * i][c4 + 0] = v.x; tile[r + 16 * i][c4 + 1] = v.y;
    tile[r + 16 * i][c4 + 2] = v.z; tile[r + 16 * i][c4 + 3] = v.w;
  }
  __syncthreads();
  const int cc = t >> 2, rr = (t & 3) * 16;
#pragma unroll
  for (int half = 0; half < 2; ++half) {
    h8 o;
#pragma unroll
    for (int j = 0; j < 8; ++j) o[j] = (_Float16)tile[rr + half * 8 + j][cc];
    *(h8*)&dst[(size_t)(c0 + cc) * EMB + r0 + rr + half * 8] = o;
  }
}

// ---------------- projection GEMM: Out[b*12+h][tok][e] = (Xh @ W + bias) * scale ----------------
__global__ __launch_bounds__(256) void k_proj(const _Float16* __restrict__ Xh,
                                              const _Float16* __restrict__ Wt,
                                              const float* __restrict__ bias,
                                              _Float16* __restrict__ Out, float scale) {
  __shared__ _Float16 As[128][40];  // [m][k]
  __shared__ _Float16 Bs[128][40];  // [n][k] (Wt layout)
  const int t = threadIdx.x;
  const int w = t >> 6, l = t & 63;
  const int wm = w >> 1, wn = w & 1;
  const int m0 = blockIdx.x * 128, n0 = blockIdx.y * 128;
  f4 acc[4][4];
#pragma unroll
  for (int mf = 0; mf < 4; ++mf)
#pragma unroll
    for (int nf = 0; nf < 4; ++nf) acc[mf][nf] = f4{0.f, 0.f, 0.f, 0.f};

  const int srow = t >> 2, sc = (t & 3) * 8;
  for (int k0 = 0; k0 < EMB; k0 += 32) {
#pragma unroll
    for (int i = 0; i < 2; ++i) {
      *(h8*)&As[srow + 64 * i][sc] = *(const h8*)&Xh[(size_t)(m0 + srow + 64 * i) * EMB + k0 + sc];
      *(h8*)&Bs[srow + 64 * i][sc] = *(const h8*)&Wt[(size_t)(n0 + srow + 64 * i) * EMB + k0 + sc];
    }
    __syncthreads();
    h8 af[4], bf[4];
#pragma unroll
    for (int mf = 0; mf < 4; ++mf) af[mf] = *(const h8*)&As[wm * 64 + mf * 16 + (l & 15)][(l >> 4) * 8];
#pragma unroll
    for (int nf = 0; nf < 4; ++nf) bf[nf] = *(const h8*)&Bs[wn * 64 + nf * 16 + (l & 15)][(l >> 4) * 8];
#pragma unroll
    for (int mf = 0; mf < 4; ++mf)
#pragma unroll
      for (int nf = 0; nf < 4; ++nf) acc[mf][nf] = mfma16(af[mf], bf[nf], acc[mf][nf]);
    __syncthreads();
  }
#pragma unroll
  for (int nf = 0; nf < 4; ++nf) {
    const int C = n0 + wn * 64 + nf * 16 + (l & 15);
    const float bvv = bias[C];
    const int h = C >> 6, e = C & 63;
#pragma unroll
    for (int mf = 0; mf < 4; ++mf) {
#pragma unroll
      for (int r = 0; r < 4; ++r) {
        const int R = m0 + wm * 64 + mf * 16 + (l >> 4) * 4 + r;
        const int b = R >> 10, tok = R & 1023;
        Out[((size_t)(b * NH + h) * NN + tok) * HD + e] = (_Float16)((acc[mf][nf][r] + bvv) * scale);
      }
    }
  }
}

// ---------------- column stats: Lg'[j] = l_j*exp(m_j - M*_tile), MT[tile] = M* ----------------
__global__ __launch_bounds__(256) void k_stats(const _Float16* __restrict__ Q,
                                               const _Float16* __restrict__ K,
                                               float* __restrict__ Lg, float* __restrict__ MT) {
  const int bh = blockIdx.y, j0 = blockIdx.x * 128;
  __shared__ _Float16 Ks[128][72];
  __shared__ _Float16 Qs[128][72];
  __shared__ float Mj[128], Lj[128];
  __shared__ float redm[2][128], reds[2][128];
  __shared__ float MsSh;
  const _Float16* Qb = Q + (size_t)bh * NN * HD;
  const _Float16* Kb = K + (size_t)bh * NN * HD;
  const int t = threadIdx.x, w = t >> 6, l = t & 63;
  const int wi = w >> 1, wj = w & 1;
  const int lr = t >> 3, c8 = (t & 7) * 8;
#pragma unroll
  for (int i = 0; i < 4; ++i)
    *(h8*)&Ks[lr + 32 * i][c8] = *(const h8*)&Kb[(size_t)(j0 + lr + 32 * i) * HD + c8];
  if (t < 128) { Mj[t] = -1e30f; Lj[t] = 0.f; }
  __syncthreads();

  for (int i0 = 0; i0 < NN; i0 += 128) {
#pragma unroll
    for (int i = 0; i < 4; ++i)
      *(h8*)&Qs[lr + 32 * i][c8] = *(const h8*)&Qb[(size_t)(i0 + lr + 32 * i) * HD + c8];
    __syncthreads();
    f4 s[4][4];
#pragma unroll
    for (int mf = 0; mf < 4; ++mf)
#pragma unroll
      for (int nf = 0; nf < 4; ++nf) s[mf][nf] = f4{0.f, 0.f, 0.f, 0.f};
#pragma unroll
    for (int ks = 0; ks < 2; ++ks) {
      h8 af[4], bf[4];
#pragma unroll
      for (int mf = 0; mf < 4; ++mf) af[mf] = *(const h8*)&Qs[wi * 64 + mf * 16 + (l & 15)][ks * 32 + (l >> 4) * 8];
#pragma unroll
      for (int nf = 0; nf < 4; ++nf) bf[nf] = *(const h8*)&Ks[wj * 64 + nf * 16 + (l & 15)][ks * 32 + (l >> 4) * 8];
#pragma unroll
      for (int mf = 0; mf < 4; ++mf)
#pragma unroll
        for (int nf = 0; nf < 4; ++nf) s[mf][nf] = mfma16(af[mf], bf[nf], s[mf][nf]);
    }
#pragma unroll
    for (int nf = 0; nf < 4; ++nf) {
      float cm = -1e30f;
#pragma unroll
      for (int mf = 0; mf < 4; ++mf)
#pragma unroll
        for (int r = 0; r < 4; ++r) cm = fmaxf(cm, s[mf][nf][r]);
      cm = fmaxf(cm, __shfl_xor(cm, 16));
      cm = fmaxf(cm, __shfl_xor(cm, 32));
      float cs = 0.f;
#pragma unroll
      for (int mf = 0; mf < 4; ++mf)
#pragma unroll
        for (int r = 0; r < 4; ++r) cs += __expf(s[mf][nf][r] - cm);
      cs += __shfl_xor(cs, 16);
      cs += __shfl_xor(cs, 32);
      if (l < 16) {
        redm[wi][wj * 64 + nf * 16 + l] = cm;
        reds[wi][wj * 64 + nf * 16 + l] = cs;
      }
    }
    __syncthreads();
    if (t < 128) {
      const float mo = Mj[t], p0 = redm[0][t], p1 = redm[1][t];
      const float nm = fmaxf(mo, fmaxf(p0, p1));
      Lj[t] = Lj[t] * __expf(mo - nm) + reds[0][t] * __expf(p0 - nm) + reds[1][t] * __expf(p1 - nm);
      Mj[t] = nm;
    }
    __syncthreads();
  }
  // tail: tile max M*, scaled denom
  if (w == 0) {
    float mv = fmaxf(Mj[l], Mj[l + 64]);
#pragma unroll
    for (int d = 32; d; d >>= 1) mv = fmaxf(mv, __shfl_xor(mv, d));
    if (l == 0) { MsSh = mv; MT[bh * 8 + blockIdx.x] = mv; }
  }
  __syncthreads();
  if (t < 128) Lg[(size_t)bh * NN + j0 + t] = Lj[t] * __expf(Mj[t] - MsSh);
}

// ---------------- V [bh][j][e] -> Vt [bh][e][j] scaled by 1/Lg'[j] ----------------
__global__ __launch_bounds__(256) void k_vt(const _Float16* __restrict__ Vtmp,
                                            const float* __restrict__ Lg,
                                            _Float16* __restrict__ Vt) {
  const int bh = blockIdx.y, j0 = blockIdx.x * 64;
  __shared__ _Float16 tile[64][72];
  const _Float16* src = Vtmp + (size_t)bh * NN * HD;
  _Float16* dst = Vt + (size_t)bh * HD * NN;
  const int t = threadIdx.x;
  const int jr = t >> 3, e8 = (t & 7) * 8;
#pragma unroll
  for (int i = 0; i < 2; ++i) {
    const float inv = 1.0f / Lg[(size_t)bh * NN + j0 + jr + 32 * i];
    h8 v = *(const h8*)&src[(size_t)(j0 + jr + 32 * i) * HD + e8];
    h8 o;
#pragma unroll
    for (int j = 0; j < 8; ++j) o[j] = (_Float16)((float)v[j] * inv);
    *(h8*)&tile[jr + 32 * i][e8] = o;
  }
  __syncthreads();
  const int er = t >> 3, j8 = (t & 7) * 8;
#pragma unroll
  for (int i = 0; i < 2; ++i) {
    h8 o;
#pragma unroll
    for (int j = 0; j < 8; ++j) o[j] = tile[j8 + j][er + 32 * i];
    *(h8*)&dst[(size_t)(er + 32 * i) * NN + j0 + j8] = o;
  }
}

// ---------------- output: out = exp(S - M*[tile]) @ V'  (S^T trick, b64/b128 P path) ------------
// Per block: i-tile 128 (4 waves x 32 rows each), j-tile 32, double-buffered K/V staging.
// S^T = mfma(A=K, B=Q): lane holds col=i, rows=j contiguous -> P write = ds_write_b64,
// PV = mfma(A=V't rows=e, B=P cols=i): B-frag = ds_read_b128 from Ps[i][j]; D[e][i] -> float4 out.
__global__ __launch_bounds__(256) void k_out(const _Float16* __restrict__ Q,
                                             const _Float16* __restrict__ K,
                                             const _Float16* __restrict__ Vt,
                                             const float* __restrict__ MT,
                                             float* __restrict__ Out) {
  const int bh = blockIdx.y, i0 = blockIdx.x * 128;
  const int b = bh / NH, h = bh % NH;
  __shared__ _Float16 Ks[2][32][72];   // [buf][j][e]
  __shared__ _Float16 Vts[2][64][36];  // [buf][e][j]
  __shared__ _Float16 Ps[4][32][36];   // [wave][i][j]  (wave-private)
  const _Float16* Qb = Q + (size_t)bh * NN * HD;
  const _Float16* Kb = K + (size_t)bh * NN * HD;
  const _Float16* Vb = Vt + (size_t)bh * HD * NN;
  const int t = threadIdx.x, w = t >> 6, l = t & 63;
  const int p = l & 15, g = l >> 4;

  // Q B-frags (col i = w*32 + if*16 + p, k = ks*32 + g*8)
  h8 bq[2][2];
#pragma unroll
  for (int f = 0; f < 2; ++f)
#pragma unroll
    for (int ks = 0; ks < 2; ++ks)
      bq[f][ks] = *(const h8*)&Qb[(size_t)(i0 + w * 32 + f * 16 + p) * HD + ks * 32 + g * 8];

  f4 oacc[4][2];  // [ef][if] -> D[e][i]
#pragma unroll
  for (int ef = 0; ef < 4; ++ef)
#pragma unroll
    for (int f = 0; f < 2; ++f) oacc[ef][f] = f4{0.f, 0.f, 0.f, 0.f};

  // staging: K 32x64 (1 b128/thread), V 64x32 (1 b128/thread)
  const int kr = t >> 3, ke = (t & 7) * 8;
  const int vr = t >> 2, vj = (t & 3) * 8;

  h8 kreg = *(const h8*)&Kb[(size_t)kr * HD + ke];
  h8 vreg = *(const h8*)&Vb[(size_t)vr * NN + vj];
  *(h8*)&Ks[0][kr][ke] = kreg;
  *(h8*)&Vts[0][vr][vj] = vreg;

  for (int jt = 0; jt < 32; ++jt) {
    const int cur = jt & 1;
    __syncthreads();  // staged buf[cur] visible to all waves
    if (jt + 1 < 32) {
      const int j0n = (jt + 1) * 32;
      kreg = *(const h8*)&Kb[(size_t)(j0n + kr) * HD + ke];
      vreg = *(const h8*)&Vb[(size_t)vr * NN + j0n + vj];
    }
    const float Mstar = MT[bh * 8 + (jt >> 2)];

    // S^T = K * Q^T : s[if][jf], col=i=f*16+p, rows j=jf*16+4g+r
    f4 s[2][2];
#pragma unroll
    for (int f = 0; f < 2; ++f)
#pragma unroll
      for (int jf = 0; jf < 2; ++jf) s[f][jf] = f4{0.f, 0.f, 0.f, 0.f};
#pragma unroll
    for (int ks = 0; ks < 2; ++ks) {
      h8 ak[2];
#pragma unroll
      for (int jf = 0; jf < 2; ++jf) ak[jf] = *(const h8*)&Ks[cur][jf * 16 + p][ks * 32 + g * 8];
#pragma unroll
      for (int f = 0; f < 2; ++f)
#pragma unroll
        for (int jf = 0; jf < 2; ++jf) s[f][jf] = mfma16(ak[jf], bq[f][ks], s[f][jf]);
    }

    // V't A-frags (independent of P) — issue early
    h8 av[4];
#pragma unroll
    for (int ef = 0; ef < 4; ++ef) av[ef] = *(const h8*)&Vts[cur][ef * 16 + p][g * 8];

    // P = exp(S - M*): 4 x ds_write_b64, j-contiguous
#pragma unroll
    for (int f = 0; f < 2; ++f)
#pragma unroll
      for (int jf = 0; jf < 2; ++jf) {
        h4 pw;
#pragma unroll
        for (int r = 0; r < 4; ++r) pw[r] = (_Float16)__expf(s[f][jf][r] - Mstar);
        *(h4*)&Ps[w][f * 16 + p][jf * 16 + 4 * g] = pw;
      }
    // wave-private P: DS pipe is in-order per wave; cheap insurance before cross-lane read
    asm volatile("s_waitcnt lgkmcnt(0)" ::: "memory");

    // PV: D[e][i] += V't[e][j] * P[i][j]
    h8 bp[2];
#pragma unroll
    for (int f = 0; f < 2; ++f) bp[f] = *(const h8*)&Ps[w][f * 16 + p][g * 8];
#pragma unroll
    for (int ef = 0; ef < 4; ++ef)
#pragma unroll
      for (int f = 0; f < 2; ++f) oacc[ef][f] = mfma16(av[ef], bp[f], oacc[ef][f]);

    // write next tile into other buffer (no barrier needed: disjoint buf)
    if (jt + 1 < 32) {
      *(h8*)&Ks[cur ^ 1][kr][ke] = kreg;
      *(h8*)&Vts[cur ^ 1][vr][vj] = vreg;
    }
  }

  // epilogue: lane (p,g): col i = i0+w*32+f*16+p, rows e = ef*16+4g+r -> float4
#pragma unroll
  for (int f = 0; f < 2; ++f) {
    const int i = i0 + w * 32 + f * 16 + p;
#pragma unroll
    for (int ef = 0; ef < 4; ++ef) {
      float4 o4 = {oacc[ef][f][0], oacc[ef][f][1], oacc[ef][f][2], oacc[ef][f][3]};
      *(float4*)&Out[((size_t)b * NN + i) * EMB + h * HD + ef * 16 + 4 * g] = o4;
    }
  }
}

extern "C" void kernel_launch(void* const* d_in, const int* in_sizes, int n_in,
                              void* d_out, int out_size, void* d_ws, size_t ws_size,
                              hipStream_t stream) {
  const float* X  = (const float*)d_in[0];
  const float* Wq = (const float*)d_in[1];
  const float* bq = (const float*)d_in[2];
  const float* Wk = (const float*)d_in[3];
  const float* bk = (const float*)d_in[4];
  const float* Wv = (const float*)d_in[5];
  const float* bv = (const float*)d_in[6];

  // workspace layout (~156.1 MB)
  char* ws = (char*)d_ws;
  _Float16* Qw = (_Float16*)(ws);                  // 50,331,648 B
  _Float16* Kw = (_Float16*)(ws + 50331648);       // 50,331,648 B
  _Float16* Vt = (_Float16*)(ws + 100663296);      // 50,331,648 B
  _Float16* Wt = (_Float16*)(ws + 150994944);      // 3 * 1,179,648 B
  float* Lg    = (float*)(ws + 154533888);         // 1,572,864 B
  float* MT    = (float*)(ws + 156106752);         // 12,288 B

  // transients inside d_out (overwritten by final f32 result at the end)
  _Float16* Xh   = (_Float16*)d_out;                        // 50,331,648 B
  _Float16* Vtmp = (_Float16*)((char*)d_out + 50331648);    // 50,331,648 B
  float* Out = (float*)d_out;

  k_cvt<<<dim3(6291456 / 256), 256, 0, stream>>>(X, Xh, 6291456);
  k_wt<<<dim3(12, 12, 3), 256, 0, stream>>>(Wq, Wk, Wv, Wt);
  k_proj<<<dim3(256, 6), 256, 0, stream>>>(Xh, Wt,           bq, Qw,   0.2886751345948129f);
  k_proj<<<dim3(256, 6), 256, 0, stream>>>(Xh, Wt + 589824,  bk, Kw,   1.0f);
  k_proj<<<dim3(256, 6), 256, 0, stream>>>(Xh, Wt + 1179648, bv, Vtmp, 1.0f);
  k_stats<<<dim3(8, 384), 256, 0, stream>>>(Qw, Kw, Lg, MT);
  k_vt<<<dim3(16, 384), 256, 0, stream>>>(Vtmp, Lg, Vt);
  k_out<<<dim3(8, 384), 256, 0, stream>>>(Qw, Kw, Vt, MT, Out);
}

// Round 6
// 490.921 us; speedup vs baseline: 1.1574x; 1.0814x over previous
//
#include <hip/hip_runtime.h>

#define EMB 768
#define NH 12
#define HD 64
#define BB 32
#define NN 1024
// log2(e)/sqrt(12): Q pre-scale so QK^T is in log2 domain
#define QSCALE 0.41647025f

typedef _Float16 h8 __attribute__((ext_vector_type(8)));
typedef _Float16 h4 __attribute__((ext_vector_type(4)));
typedef _Float16 h2 __attribute__((ext_vector_type(2)));
typedef float f4 __attribute__((ext_vector_type(4)));

static __device__ __forceinline__ f4 mfma16(h8 a, h8 b, f4 c) {
  return __builtin_amdgcn_mfma_f32_16x16x32_f16(a, b, c, 0, 0, 0);
}

static __device__ __forceinline__ h2 cvt_pk(float a, float b) {
  return __builtin_bit_cast(h2, __builtin_amdgcn_cvt_pkrtz(a, b));
}

static __device__ __forceinline__ float exp2a(float x) {
#if __has_builtin(__builtin_amdgcn_exp2f)
  return __builtin_amdgcn_exp2f(x);
#else
  float r;
  asm("v_exp_f32 %0, %1\n\ts_nop 1" : "=v"(r) : "v"(x));
  return r;
#endif
}

// ---------------- X f32 -> f16 ----------------
__global__ __launch_bounds__(256) void k_cvt(const float* __restrict__ X,
                                             _Float16* __restrict__ Xh, int n4) {
  int i = blockIdx.x * 256 + threadIdx.x;
  if (i >= n4) return;
  float4 v = ((const float4*)X)[i];
  h4 o = {(_Float16)v.x, (_Float16)v.y, (_Float16)v.z, (_Float16)v.w};
  ((h4*)Xh)[i] = o;
}

// ---------------- W (768x768 f32) -> W^T f16, all three ----------------
__global__ __launch_bounds__(256) void k_wt(const float* __restrict__ W0,
                                            const float* __restrict__ W1,
                                            const float* __restrict__ W2,
                                            _Float16* __restrict__ Wt) {
  const float* W = blockIdx.z == 0 ? W0 : (blockIdx.z == 1 ? W1 : W2);
  _Float16* dst = Wt + (size_t)blockIdx.z * EMB * EMB;
  __shared__ float tile[64][65];
  const int t = threadIdx.x;
  const int r0 = blockIdx.y * 64, c0 = blockIdx.x * 64;
  const int r = t >> 4, c4 = (t & 15) * 4;
#pragma unroll
  for (int i = 0; i < 4; ++i) {
    const float4 v = *(const float4*)&W[(size_t)(r0 + r + 16 * i) * EMB + c0 + c4];
    tile[r + 16 * i][c4 + 0] = v.x; tile[r + 16 * i][c4 + 1] = v.y;
    tile[r + 16 * i][c4 + 2] = v.z; tile[r + 16 * i][c4 + 3] = v.w;
  }
  __syncthreads();
  const int cc = t >> 2, rr = (t & 3) * 16;
#pragma unroll
  for (int half = 0; half < 2; ++half) {
    h8 o;
#pragma unroll
    for (int j = 0; j < 8; ++j) o[j] = (_Float16)tile[rr + half * 8 + j][cc];
    *(h8*)&dst[(size_t)(c0 + cc) * EMB + r0 + rr + half * 8] = o;
  }
}

// ---------------- projection GEMM: Out[b*12+h][tok][e] = (Xh @ W + bias) * scale ----------------
__global__ __launch_bounds__(256) void k_proj(const _Float16* __restrict__ Xh,
                                              const _Float16* __restrict__ Wt,
                                              const float* __restrict__ bias,
                                              _Float16* __restrict__ Out, float scale) {
  __shared__ _Float16 As[128][40];  // [m][k]
  __shared__ _Float16 Bs[128][40];  // [n][k] (Wt layout)
  const int t = threadIdx.x;
  const int w = t >> 6, l = t & 63;
  const int wm = w >> 1, wn = w & 1;
  const int m0 = blockIdx.x * 128, n0 = blockIdx.y * 128;
  f4 acc[4][4];
#pragma unroll
  for (int mf = 0; mf < 4; ++mf)
#pragma unroll
    for (int nf = 0; nf < 4; ++nf) acc[mf][nf] = f4{0.f, 0.f, 0.f, 0.f};

  const int srow = t >> 2, sc = (t & 3) * 8;
  for (int k0 = 0; k0 < EMB; k0 += 32) {
#pragma unroll
    for (int i = 0; i < 2; ++i) {
      *(h8*)&As[srow + 64 * i][sc] = *(const h8*)&Xh[(size_t)(m0 + srow + 64 * i) * EMB + k0 + sc];
      *(h8*)&Bs[srow + 64 * i][sc] = *(const h8*)&Wt[(size_t)(n0 + srow + 64 * i) * EMB + k0 + sc];
    }
    __syncthreads();
    h8 af[4], bf[4];
#pragma unroll
    for (int mf = 0; mf < 4; ++mf) af[mf] = *(const h8*)&As[wm * 64 + mf * 16 + (l & 15)][(l >> 4) * 8];
#pragma unroll
    for (int nf = 0; nf < 4; ++nf) bf[nf] = *(const h8*)&Bs[wn * 64 + nf * 16 + (l & 15)][(l >> 4) * 8];
#pragma unroll
    for (int mf = 0; mf < 4; ++mf)
#pragma unroll
      for (int nf = 0; nf < 4; ++nf) acc[mf][nf] = mfma16(af[mf], bf[nf], acc[mf][nf]);
    __syncthreads();
  }
#pragma unroll
  for (int nf = 0; nf < 4; ++nf) {
    const int C = n0 + wn * 64 + nf * 16 + (l & 15);
    const float bvv = bias[C];
    const int h = C >> 6, e = C & 63;
#pragma unroll
    for (int mf = 0; mf < 4; ++mf) {
#pragma unroll
      for (int r = 0; r < 4; ++r) {
        const int R = m0 + wm * 64 + mf * 16 + (l >> 4) * 4 + r;
        const int b = R >> 10, tok = R & 1023;
        Out[((size_t)(b * NH + h) * NN + tok) * HD + e] = (_Float16)((acc[mf][nf][r] + bvv) * scale);
      }
    }
  }
}

// ---------------- column stats (log2 domain): Lg'[j] = l_j*2^(m'_j - M*'), MT = M*' ----------------
__global__ __launch_bounds__(256) void k_stats(const _Float16* __restrict__ Q,
                                               const _Float16* __restrict__ K,
                                               float* __restrict__ Lg, float* __restrict__ MT) {
  const int bh = blockIdx.x * 48 + (blockIdx.y >> 3);   // XCD-aware: bx = XCD
  const int jt = blockIdx.y & 7;
  const int j0 = jt * 128;
  __shared__ _Float16 Ks[128][64];  // 128B rows, XOR-swizzled chunks (mask 7)
  __shared__ _Float16 Qs[128][64];
  __shared__ float Mj[128], Lj[128];
  __shared__ float redm[2][128], reds[2][128];
  __shared__ float MsSh;
  const _Float16* Qb = Q + (size_t)bh * NN * HD;
  const _Float16* Kb = K + (size_t)bh * NN * HD;
  const int t = threadIdx.x, w = t >> 6, l = t & 63;
  const int wi = w >> 1, wj = w & 1;
  const int p = l & 15, g = l >> 4;
  const int lr = t >> 3, tc = t & 7;  // staging: row lr(+32i), chunk tc
  char* ksb = (char*)&Ks[0][0];
  char* qsb = (char*)&Qs[0][0];
#pragma unroll
  for (int i = 0; i < 4; ++i)
    *(h8*)(ksb + ((lr + 32 * i) << 7) + ((tc ^ (lr & 7)) << 4)) =
        *(const h8*)&Kb[(size_t)(j0 + lr + 32 * i) * HD + tc * 8];
  if (t < 128) { Mj[t] = -1e30f; Lj[t] = 0.f; }
  __syncthreads();

  for (int i0 = 0; i0 < NN; i0 += 128) {
#pragma unroll
    for (int i = 0; i < 4; ++i)
      *(h8*)(qsb + ((lr + 32 * i) << 7) + ((tc ^ (lr & 7)) << 4)) =
          *(const h8*)&Qb[(size_t)(i0 + lr + 32 * i) * HD + tc * 8];
    __syncthreads();
    f4 s[4][4];
#pragma unroll
    for (int mf = 0; mf < 4; ++mf)
#pragma unroll
      for (int nf = 0; nf < 4; ++nf) s[mf][nf] = f4{0.f, 0.f, 0.f, 0.f};
#pragma unroll
    for (int ks = 0; ks < 2; ++ks) {
      h8 af[4], bf[4];
#pragma unroll
      for (int mf = 0; mf < 4; ++mf)
        af[mf] = *(const h8*)(qsb + ((wi * 64 + mf * 16 + p) << 7) + ((((ks << 2) | g) ^ (p & 7)) << 4));
#pragma unroll
      for (int nf = 0; nf < 4; ++nf)
        bf[nf] = *(const h8*)(ksb + ((wj * 64 + nf * 16 + p) << 7) + ((((ks << 2) | g) ^ (p & 7)) << 4));
#pragma unroll
      for (int mf = 0; mf < 4; ++mf)
#pragma unroll
        for (int nf = 0; nf < 4; ++nf) s[mf][nf] = mfma16(af[mf], bf[nf], s[mf][nf]);
    }
#pragma unroll
    for (int nf = 0; nf < 4; ++nf) {
      float cm = -1e30f;
#pragma unroll
      for (int mf = 0; mf < 4; ++mf)
#pragma unroll
        for (int r = 0; r < 4; ++r) cm = fmaxf(cm, s[mf][nf][r]);
      cm = fmaxf(cm, __shfl_xor(cm, 16));
      cm = fmaxf(cm, __shfl_xor(cm, 32));
      float cs = 0.f;
#pragma unroll
      for (int mf = 0; mf < 4; ++mf)
#pragma unroll
        for (int r = 0; r < 4; ++r) cs += exp2a(s[mf][nf][r] - cm);
      cs += __shfl_xor(cs, 16);
      cs += __shfl_xor(cs, 32);
      if (l < 16) {
        redm[wi][wj * 64 + nf * 16 + l] = cm;
        reds[wi][wj * 64 + nf * 16 + l] = cs;
      }
    }
    __syncthreads();
    if (t < 128) {
      const float mo = Mj[t], p0 = redm[0][t], p1 = redm[1][t];
      const float nm = fmaxf(mo, fmaxf(p0, p1));
      Lj[t] = Lj[t] * exp2a(mo - nm) + reds[0][t] * exp2a(p0 - nm) + reds[1][t] * exp2a(p1 - nm);
      Mj[t] = nm;
    }
    __syncthreads();
  }
  // tail: tile max M*', scaled denom
  if (w == 0) {
    float mv = fmaxf(Mj[l], Mj[l + 64]);
#pragma unroll
    for (int d = 32; d; d >>= 1) mv = fmaxf(mv, __shfl_xor(mv, d));
    if (l == 0) { MsSh = mv; MT[bh * 8 + jt] = mv; }
  }
  __syncthreads();
  if (t < 128) Lg[(size_t)bh * NN + j0 + t] = Lj[t] * exp2a(Mj[t] - MsSh);
}

// ---------------- V [bh][j][e] -> Vt [bh][e][j] scaled by 1/Lg'[j] ----------------
__global__ __launch_bounds__(256) void k_vt(const _Float16* __restrict__ Vtmp,
                                            const float* __restrict__ Lg,
                                            _Float16* __restrict__ Vt) {
  const int bh = blockIdx.y, j0 = blockIdx.x * 64;
  __shared__ _Float16 tile[64][72];
  const _Float16* src = Vtmp + (size_t)bh * NN * HD;
  _Float16* dst = Vt + (size_t)bh * HD * NN;
  const int t = threadIdx.x;
  const int jr = t >> 3, e8 = (t & 7) * 8;
#pragma unroll
  for (int i = 0; i < 2; ++i) {
    const float inv = 1.0f / Lg[(size_t)bh * NN + j0 + jr + 32 * i];
    h8 v = *(const h8*)&src[(size_t)(j0 + jr + 32 * i) * HD + e8];
    h8 o;
#pragma unroll
    for (int j = 0; j < 8; ++j) o[j] = (_Float16)((float)v[j] * inv);
    *(h8*)&tile[jr + 32 * i][e8] = o;
  }
  __syncthreads();
  const int er = t >> 3, j8 = (t & 7) * 8;
#pragma unroll
  for (int i = 0; i < 2; ++i) {
    h8 o;
#pragma unroll
    for (int j = 0; j < 8; ++j) o[j] = tile[j8 + j][er + 32 * i];
    *(h8*)&dst[(size_t)(er + 32 * i) * NN + j0 + j8] = o;
  }
}

// ---------------- output: out = 2^(S' - M*') @ V'  (S^T trick, swizzled LDS) ----------------
__global__ __launch_bounds__(256) void k_out(const _Float16* __restrict__ Q,
                                             const _Float16* __restrict__ K,
                                             const _Float16* __restrict__ Vt,
                                             const float* __restrict__ MT,
                                             float* __restrict__ Out) {
  const int bh = blockIdx.x * 48 + (blockIdx.y >> 3);   // XCD-aware: bx = XCD
  const int i0 = (blockIdx.y & 7) * 128;
  const int b = bh / NH, h = bh % NH;
  __shared__ _Float16 Ks[2][32][64];   // [buf][j][e], 128B rows, swz mask 7
  __shared__ _Float16 Vts[2][64][32];  // [buf][e][j], 64B rows, swz (row>>1)&3
  __shared__ _Float16 Ps[4][32][32];   // [wave][i][j], 64B rows, swz (row>>1)&3
  const _Float16* Qb = Q + (size_t)bh * NN * HD;
  const _Float16* Kb = K + (size_t)bh * NN * HD;
  const _Float16* Vb = Vt + (size_t)bh * HD * NN;
  const int t = threadIdx.x, w = t >> 6, l = t & 63;
  const int p = l & 15, g = l >> 4;
  char* psb = (char*)&Ps[w][0][0];

  // Q B-frags (col i = w*32 + f*16 + p, k = ks*32 + g*8)
  h8 bq[2][2];
#pragma unroll
  for (int f = 0; f < 2; ++f)
#pragma unroll
    for (int ks = 0; ks < 2; ++ks)
      bq[f][ks] = *(const h8*)&Qb[(size_t)(i0 + w * 32 + f * 16 + p) * HD + ks * 32 + g * 8];

  f4 oacc[4][2];  // [ef][if] -> D[e][i]
#pragma unroll
  for (int ef = 0; ef < 4; ++ef)
#pragma unroll
    for (int f = 0; f < 2; ++f) oacc[ef][f] = f4{0.f, 0.f, 0.f, 0.f};

  // staging: K 32x64 (row kr, chunk kc), V 64x32 (row vr, chunk vc)
  const int kr = t >> 3, kc = t & 7;
  const int vr = t >> 2, vc = t & 3;

  h8 kreg = *(const h8*)&Kb[(size_t)kr * HD + kc * 8];
  h8 vreg = *(const h8*)&Vb[(size_t)vr * NN + vc * 8];
  *(h8*)((char*)&Ks[0][0][0] + (kr << 7) + ((kc ^ (kr & 7)) << 4)) = kreg;
  *(h8*)((char*)&Vts[0][0][0] + (vr << 6) + ((vc ^ ((vr >> 1) & 3)) << 4)) = vreg;

  for (int jt = 0; jt < 32; ++jt) {
    const int cur = jt & 1;
    char* ksb = (char*)&Ks[cur][0][0];
    char* vsb = (char*)&Vts[cur][0][0];
    __syncthreads();  // staged buf[cur] visible; prev reads of buf[cur^1] done
    if (jt + 1 < 32) {
      const int j0n = (jt + 1) * 32;
      kreg = *(const h8*)&Kb[(size_t)(j0n + kr) * HD + kc * 8];
      vreg = *(const h8*)&Vb[(size_t)vr * NN + j0n + vc * 8];
    }
    const float Mstar = MT[bh * 8 + (jt >> 2)];

    // S'^T = K * Q^T, acc pre-init to -M*' (kills the sub)
    f4 s[2][2];
#pragma unroll
    for (int f = 0; f < 2; ++f)
#pragma unroll
      for (int jf = 0; jf < 2; ++jf) s[f][jf] = f4{-Mstar, -Mstar, -Mstar, -Mstar};
#pragma unroll
    for (int ks = 0; ks < 2; ++ks) {
      h8 ak[2];
#pragma unroll
      for (int jf = 0; jf < 2; ++jf)
        ak[jf] = *(const h8*)(ksb + ((jf * 16 + p) << 7) + ((((ks << 2) | g) ^ (p & 7)) << 4));
#pragma unroll
      for (int f = 0; f < 2; ++f)
#pragma unroll
        for (int jf = 0; jf < 2; ++jf) s[f][jf] = mfma16(ak[jf], bq[f][ks], s[f][jf]);
    }

    // V't A-frags (independent of P) — issue early
    h8 av[4];
#pragma unroll
    for (int ef = 0; ef < 4; ++ef)
      av[ef] = *(const h8*)(vsb + ((ef * 16 + p) << 6) + ((g ^ ((p >> 1) & 3)) << 4));

    // P = 2^(S' - M*'): v_exp + packed cvt, one ds_write_b64 per 16x16 block
#pragma unroll
    for (int f = 0; f < 2; ++f)
#pragma unroll
      for (int jf = 0; jf < 2; ++jf) {
        const f4 sv = s[f][jf];
        h2 lo = cvt_pk(exp2a(sv[0]), exp2a(sv[1]));
        h2 hi = cvt_pk(exp2a(sv[2]), exp2a(sv[3]));
        h4 pw; pw[0] = lo[0]; pw[1] = lo[1]; pw[2] = hi[0]; pw[3] = hi[1];
        *(h4*)(psb + ((f * 16 + p) << 6) +
               (((2 * jf + (g >> 1)) ^ ((p >> 1) & 3)) << 4) + ((g & 1) << 3)) = pw;
      }
    // wave-private P: DS in-order per wave; cheap insurance before cross-lane read
    asm volatile("s_waitcnt lgkmcnt(0)" ::: "memory");

    // PV: D[e][i] += V't[e][j] * P[i][j]
    h8 bp[2];
#pragma unroll
    for (int f = 0; f < 2; ++f)
      bp[f] = *(const h8*)(psb + ((f * 16 + p) << 6) + ((g ^ ((p >> 1) & 3)) << 4));
#pragma unroll
    for (int ef = 0; ef < 4; ++ef)
#pragma unroll
      for (int f = 0; f < 2; ++f) oacc[ef][f] = mfma16(av[ef], bp[f], oacc[ef][f]);

    // write next tile into other buffer (no barrier needed: disjoint buf)
    if (jt + 1 < 32) {
      *(h8*)((char*)&Ks[cur ^ 1][0][0] + (kr << 7) + ((kc ^ (kr & 7)) << 4)) = kreg;
      *(h8*)((char*)&Vts[cur ^ 1][0][0] + (vr << 6) + ((vc ^ ((vr >> 1) & 3)) << 4)) = vreg;
    }
  }

  // epilogue: lane (p,g): col i = i0+w*32+f*16+p, rows e = ef*16+4g+r -> float4
#pragma unroll
  for (int f = 0; f < 2; ++f) {
    const int i = i0 + w * 32 + f * 16 + p;
#pragma unroll
    for (int ef = 0; ef < 4; ++ef) {
      float4 o4 = {oacc[ef][f][0], oacc[ef][f][1], oacc[ef][f][2], oacc[ef][f][3]};
      *(float4*)&Out[((size_t)b * NN + i) * EMB + h * HD + ef * 16 + 4 * g] = o4;
    }
  }
}

extern "C" void kernel_launch(void* const* d_in, const int* in_sizes, int n_in,
                              void* d_out, int out_size, void* d_ws, size_t ws_size,
                              hipStream_t stream) {
  const float* X  = (const float*)d_in[0];
  const float* Wq = (const float*)d_in[1];
  const float* bq = (const float*)d_in[2];
  const float* Wk = (const float*)d_in[3];
  const float* bk = (const float*)d_in[4];
  const float* Wv = (const float*)d_in[5];
  const float* bv = (const float*)d_in[6];

  // workspace layout (~156.1 MB)
  char* ws = (char*)d_ws;
  _Float16* Qw = (_Float16*)(ws);                  // 50,331,648 B
  _Float16* Kw = (_Float16*)(ws + 50331648);       // 50,331,648 B
  _Float16* Vt = (_Float16*)(ws + 100663296);      // 50,331,648 B
  _Float16* Wt = (_Float16*)(ws + 150994944);      // 3 * 1,179,648 B
  float* Lg    = (float*)(ws + 154533888);         // 1,572,864 B
  float* MT    = (float*)(ws + 156106752);         // 12,288 B

  // transients inside d_out (overwritten by final f32 result at the end)
  _Float16* Xh   = (_Float16*)d_out;                        // 50,331,648 B
  _Float16* Vtmp = (_Float16*)((char*)d_out + 50331648);    // 50,331,648 B
  float* Out = (float*)d_out;

  k_cvt<<<dim3(6291456 / 256), 256, 0, stream>>>(X, Xh, 6291456);
  k_wt<<<dim3(12, 12, 3), 256, 0, stream>>>(Wq, Wk, Wv, Wt);
  k_proj<<<dim3(256, 6), 256, 0, stream>>>(Xh, Wt,           bq, Qw,   QSCALE);
  k_proj<<<dim3(256, 6), 256, 0, stream>>>(Xh, Wt + 589824,  bk, Kw,   1.0f);
  k_proj<<<dim3(256, 6), 256, 0, stream>>>(Xh, Wt + 1179648, bv, Vtmp, 1.0f);
  k_stats<<<dim3(8, 384), 256, 0, stream>>>(Qw, Kw, Lg, MT);
  k_vt<<<dim3(16, 384), 256, 0, stream>>>(Vtmp, Lg, Vt);
  k_out<<<dim3(8, 384), 256, 0, stream>>>(Qw, Kw, Vt, MT, Out);
}

// Round 7
// 447.000 us; speedup vs baseline: 1.2711x; 1.0983x over previous
//
#include <hip/hip_runtime.h>

#define EMB 768
#define NH 12
#define HD 64
#define BB 32
#define NN 1024
// log2(e)/sqrt(12): Q pre-scale so QK^T is in log2 domain
#define QSCALE 0.41647025f

typedef _Float16 h8 __attribute__((ext_vector_type(8)));
typedef _Float16 h4 __attribute__((ext_vector_type(4)));
typedef _Float16 h2 __attribute__((ext_vector_type(2)));
typedef float f4 __attribute__((ext_vector_type(4)));

static __device__ __forceinline__ f4 mfma16(h8 a, h8 b, f4 c) {
  return __builtin_amdgcn_mfma_f32_16x16x32_f16(a, b, c, 0, 0, 0);
}

static __device__ __forceinline__ h2 cvt_pk(float a, float b) {
  return __builtin_bit_cast(h2, __builtin_amdgcn_cvt_pkrtz(a, b));
}

static __device__ __forceinline__ float exp2a(float x) {
#if __has_builtin(__builtin_amdgcn_exp2f)
  return __builtin_amdgcn_exp2f(x);
#else
  float r;
  asm("v_exp_f32 %0, %1\n\ts_nop 1" : "=v"(r) : "v"(x));
  return r;
#endif
}

// ---------------- X f32 -> f16 ----------------
__global__ __launch_bounds__(256) void k_cvt(const float* __restrict__ X,
                                             _Float16* __restrict__ Xh, int n4) {
  int i = blockIdx.x * 256 + threadIdx.x;
  if (i >= n4) return;
  float4 v = ((const float4*)X)[i];
  h4 o = {(_Float16)v.x, (_Float16)v.y, (_Float16)v.z, (_Float16)v.w};
  ((h4*)Xh)[i] = o;
}

// ---------------- W (768x768 f32) -> W^T f16, all three ----------------
__global__ __launch_bounds__(256) void k_wt(const float* __restrict__ W0,
                                            const float* __restrict__ W1,
                                            const float* __restrict__ W2,
                                            _Float16* __restrict__ Wt) {
  const float* W = blockIdx.z == 0 ? W0 : (blockIdx.z == 1 ? W1 : W2);
  _Float16* dst = Wt + (size_t)blockIdx.z * EMB * EMB;
  __shared__ float tile[64][65];
  const int t = threadIdx.x;
  const int r0 = blockIdx.y * 64, c0 = blockIdx.x * 64;
  const int r = t >> 4, c4 = (t & 15) * 4;
#pragma unroll
  for (int i = 0; i < 4; ++i) {
    const float4 v = *(const float4*)&W[(size_t)(r0 + r + 16 * i) * EMB + c0 + c4];
    tile[r + 16 * i][c4 + 0] = v.x; tile[r + 16 * i][c4 + 1] = v.y;
    tile[r + 16 * i][c4 + 2] = v.z; tile[r + 16 * i][c4 + 3] = v.w;
  }
  __syncthreads();
  const int cc = t >> 2, rr = (t & 3) * 16;
#pragma unroll
  for (int half = 0; half < 2; ++half) {
    h8 o;
#pragma unroll
    for (int j = 0; j < 8; ++j) o[j] = (_Float16)tile[rr + half * 8 + j][cc];
    *(h8*)&dst[(size_t)(c0 + cc) * EMB + r0 + rr + half * 8] = o;
  }
}

// ---------------- projection GEMM: Out[b*12+h][tok][e] = (Xh @ W + bias) * scale ----------------
__global__ __launch_bounds__(256) void k_proj(const _Float16* __restrict__ Xh,
                                              const _Float16* __restrict__ Wt,
                                              const float* __restrict__ bias,
                                              _Float16* __restrict__ Out, float scale) {
  __shared__ _Float16 As[128][40];  // [m][k]
  __shared__ _Float16 Bs[128][40];  // [n][k] (Wt layout)
  const int t = threadIdx.x;
  const int w = t >> 6, l = t & 63;
  const int wm = w >> 1, wn = w & 1;
  const int m0 = blockIdx.x * 128, n0 = blockIdx.y * 128;
  f4 acc[4][4];
#pragma unroll
  for (int mf = 0; mf < 4; ++mf)
#pragma unroll
    for (int nf = 0; nf < 4; ++nf) acc[mf][nf] = f4{0.f, 0.f, 0.f, 0.f};

  const int srow = t >> 2, sc = (t & 3) * 8;
  for (int k0 = 0; k0 < EMB; k0 += 32) {
#pragma unroll
    for (int i = 0; i < 2; ++i) {
      *(h8*)&As[srow + 64 * i][sc] = *(const h8*)&Xh[(size_t)(m0 + srow + 64 * i) * EMB + k0 + sc];
      *(h8*)&Bs[srow + 64 * i][sc] = *(const h8*)&Wt[(size_t)(n0 + srow + 64 * i) * EMB + k0 + sc];
    }
    __syncthreads();
    h8 af[4], bf[4];
#pragma unroll
    for (int mf = 0; mf < 4; ++mf) af[mf] = *(const h8*)&As[wm * 64 + mf * 16 + (l & 15)][(l >> 4) * 8];
#pragma unroll
    for (int nf = 0; nf < 4; ++nf) bf[nf] = *(const h8*)&Bs[wn * 64 + nf * 16 + (l & 15)][(l >> 4) * 8];
#pragma unroll
    for (int mf = 0; mf < 4; ++mf)
#pragma unroll
      for (int nf = 0; nf < 4; ++nf) acc[mf][nf] = mfma16(af[mf], bf[nf], acc[mf][nf]);
    __syncthreads();
  }
#pragma unroll
  for (int nf = 0; nf < 4; ++nf) {
    const int C = n0 + wn * 64 + nf * 16 + (l & 15);
    const float bvv = bias[C];
    const int h = C >> 6, e = C & 63;
#pragma unroll
    for (int mf = 0; mf < 4; ++mf) {
#pragma unroll
      for (int r = 0; r < 4; ++r) {
        const int R = m0 + wm * 64 + mf * 16 + (l >> 4) * 4 + r;
        const int b = R >> 10, tok = R & 1023;
        Out[((size_t)(b * NH + h) * NN + tok) * HD + e] = (_Float16)((acc[mf][nf][r] + bvv) * scale);
      }
    }
  }
}

// ---------------- column stats (log2, NO max): l~_j = sum_i 2^S'; MT = log2(max_j l~) ----------------
__global__ __launch_bounds__(256) void k_stats(const _Float16* __restrict__ Q,
                                               const _Float16* __restrict__ K,
                                               float* __restrict__ Lg, float* __restrict__ MT) {
  const int bh = blockIdx.x * 48 + (blockIdx.y >> 3);   // XCD-aware: bx = XCD
  const int jt = blockIdx.y & 7;
  const int j0 = jt * 128;
  __shared__ _Float16 Ks[128][64];  // 128B rows, XOR-swizzled chunks (mask 7)
  __shared__ _Float16 Qs[128][64];
  __shared__ float Lj[128];
  __shared__ float reds[2][128];
  __shared__ float MsSh;
  const _Float16* Qb = Q + (size_t)bh * NN * HD;
  const _Float16* Kb = K + (size_t)bh * NN * HD;
  const int t = threadIdx.x, w = t >> 6, l = t & 63;
  const int wi = w >> 1, wj = w & 1;
  const int p = l & 15, g = l >> 4;
  const int lr = t >> 3, tc = t & 7;  // staging: row lr(+32i), chunk tc
  char* ksb = (char*)&Ks[0][0];
  char* qsb = (char*)&Qs[0][0];
#pragma unroll
  for (int i = 0; i < 4; ++i)
    *(h8*)(ksb + ((lr + 32 * i) << 7) + ((tc ^ (lr & 7)) << 4)) =
        *(const h8*)&Kb[(size_t)(j0 + lr + 32 * i) * HD + tc * 8];
  if (t < 128) Lj[t] = 0.f;
  __syncthreads();

  for (int i0 = 0; i0 < NN; i0 += 128) {
#pragma unroll
    for (int i = 0; i < 4; ++i)
      *(h8*)(qsb + ((lr + 32 * i) << 7) + ((tc ^ (lr & 7)) << 4)) =
          *(const h8*)&Qb[(size_t)(i0 + lr + 32 * i) * HD + tc * 8];
    __syncthreads();
    f4 s[4][4];
#pragma unroll
    for (int mf = 0; mf < 4; ++mf)
#pragma unroll
      for (int nf = 0; nf < 4; ++nf) s[mf][nf] = f4{0.f, 0.f, 0.f, 0.f};
#pragma unroll
    for (int ks = 0; ks < 2; ++ks) {
      h8 af[4], bf[4];
#pragma unroll
      for (int mf = 0; mf < 4; ++mf)
        af[mf] = *(const h8*)(qsb + ((wi * 64 + mf * 16 + p) << 7) + ((((ks << 2) | g) ^ (p & 7)) << 4));
#pragma unroll
      for (int nf = 0; nf < 4; ++nf)
        bf[nf] = *(const h8*)(ksb + ((wj * 64 + nf * 16 + p) << 7) + ((((ks << 2) | g) ^ (p & 7)) << 4));
#pragma unroll
      for (int mf = 0; mf < 4; ++mf)
#pragma unroll
        for (int nf = 0; nf < 4; ++nf) s[mf][nf] = mfma16(af[mf], bf[nf], s[mf][nf]);
    }
    // direct f32 exp-sum over i (no max needed: |S'| bounded, f32 range ample)
#pragma unroll
    for (int nf = 0; nf < 4; ++nf) {
      float cs = 0.f;
#pragma unroll
      for (int mf = 0; mf < 4; ++mf)
#pragma unroll
        for (int r = 0; r < 4; ++r) cs += exp2a(s[mf][nf][r]);
      cs += __shfl_xor(cs, 16);
      cs += __shfl_xor(cs, 32);
      if (l < 16) reds[wi][wj * 64 + nf * 16 + l] = cs;
    }
    __syncthreads();
    if (t < 128) Lj[t] += reds[0][t] + reds[1][t];
    __syncthreads();
  }
  // tail: M* = log2(max_j l~_j)  (guarantees P = 2^(S'-M*) <= 1); Lg = l~ * 2^-M*
  if (w == 0) {
    float mv = fmaxf(Lj[l], Lj[l + 64]);
#pragma unroll
    for (int d = 32; d; d >>= 1) mv = fmaxf(mv, __shfl_xor(mv, d));
    if (l == 0) { MsSh = __log2f(mv); MT[bh * 8 + jt] = MsSh; }
  }
  __syncthreads();
  const float msc = exp2a(-MsSh);
  if (t < 128) Lg[(size_t)bh * NN + j0 + t] = Lj[t] * msc;
}

// ---------------- V [bh][j][e] -> Vt [bh][e][j] scaled by 1/Lg'[j] ----------------
__global__ __launch_bounds__(256) void k_vt(const _Float16* __restrict__ Vtmp,
                                            const float* __restrict__ Lg,
                                            _Float16* __restrict__ Vt) {
  const int bh = blockIdx.y, j0 = blockIdx.x * 64;
  __shared__ _Float16 tile[64][72];
  const _Float16* src = Vtmp + (size_t)bh * NN * HD;
  _Float16* dst = Vt + (size_t)bh * HD * NN;
  const int t = threadIdx.x;
  const int jr = t >> 3, e8 = (t & 7) * 8;
#pragma unroll
  for (int i = 0; i < 2; ++i) {
    const float inv = 1.0f / Lg[(size_t)bh * NN + j0 + jr + 32 * i];
    h8 v = *(const h8*)&src[(size_t)(j0 + jr + 32 * i) * HD + e8];
    h8 o;
#pragma unroll
    for (int j = 0; j < 8; ++j) o[j] = (_Float16)((float)v[j] * inv);
    *(h8*)&tile[jr + 32 * i][e8] = o;
  }
  __syncthreads();
  const int er = t >> 3, j8 = (t & 7) * 8;
#pragma unroll
  for (int i = 0; i < 2; ++i) {
    h8 o;
#pragma unroll
    for (int j = 0; j < 8; ++j) o[j] = tile[j8 + j][er + 32 * i];
    *(h8*)&dst[(size_t)(er + 32 * i) * NN + j0 + j8] = o;
  }
}

// ---------------- output: out = 2^(S' - M*) @ V'  (S^T trick; 2 i-tiles/block; unroll-4) ---------
__global__ __launch_bounds__(256) void k_out(const _Float16* __restrict__ Q,
                                             const _Float16* __restrict__ K,
                                             const _Float16* __restrict__ Vt,
                                             const float* __restrict__ MT,
                                             float* __restrict__ Out) {
  const int bh = blockIdx.x * 48 + (blockIdx.y >> 2);   // XCD-aware: bx = XCD
  const int i0 = (blockIdx.y & 3) * 256;
  const int b = bh / NH, h = bh % NH;
  __shared__ _Float16 Ks[2][32][64];      // [buf][j][e], 128B rows, swz mask 7
  __shared__ _Float16 Vts[2][64][32];     // [buf][e][j], 64B rows, swz (row>>1)&3
  __shared__ _Float16 Ps[4][2][32][32];   // [wave][it][i][j], wave-private
  const _Float16* Qb = Q + (size_t)bh * NN * HD;
  const _Float16* Kb = K + (size_t)bh * NN * HD;
  const _Float16* Vb = Vt + (size_t)bh * HD * NN;
  const int t = threadIdx.x, w = t >> 6, l = t & 63;
  const int p = l & 15, g = l >> 4;
  char* psb[2] = {(char*)&Ps[w][0][0][0], (char*)&Ps[w][1][0][0]};

  // Q B-frags for both i-tiles (col i = i0 + it*128 + w*32 + f*16 + p)
  h8 bq[2][2][2];
#pragma unroll
  for (int it = 0; it < 2; ++it)
#pragma unroll
    for (int f = 0; f < 2; ++f)
#pragma unroll
      for (int ks = 0; ks < 2; ++ks)
        bq[it][f][ks] = *(const h8*)&Qb[(size_t)(i0 + it * 128 + w * 32 + f * 16 + p) * HD + ks * 32 + g * 8];

  f4 oacc[2][4][2];  // [it][ef][if] -> D[e][i]
#pragma unroll
  for (int it = 0; it < 2; ++it)
#pragma unroll
    for (int ef = 0; ef < 4; ++ef)
#pragma unroll
      for (int f = 0; f < 2; ++f) oacc[it][ef][f] = f4{0.f, 0.f, 0.f, 0.f};

  // staging: K 32x64 (row kr, chunk kc), V 64x32 (row vr, chunk vc)
  const int kr = t >> 3, kc = t & 7;
  const int vr = t >> 2, vc = t & 3;

  h8 kreg = *(const h8*)&Kb[(size_t)kr * HD + kc * 8];
  h8 vreg = *(const h8*)&Vb[(size_t)vr * NN + vc * 8];
  *(h8*)((char*)&Ks[0][0][0] + (kr << 7) + ((kc ^ (kr & 7)) << 4)) = kreg;
  *(h8*)((char*)&Vts[0][0][0] + (vr << 6) + ((vc ^ ((vr >> 1) & 3)) << 4)) = vreg;

  for (int jt4 = 0; jt4 < 8; ++jt4) {
    const float Mstar = MT[bh * 8 + jt4];
#pragma unroll
    for (int u = 0; u < 4; ++u) {
      const int jt = jt4 * 4 + u;
      const int cur = u & 1;  // jt4*4 even -> jt&1 == u&1 (static)
      char* ksb = (char*)&Ks[cur][0][0];
      char* vsb = (char*)&Vts[cur][0][0];
      __syncthreads();  // staged buf[cur] visible; prev reads of buf[cur^1] done
      if (jt + 1 < 32) {
        const int j0n = (jt + 1) * 32;
        kreg = *(const h8*)&Kb[(size_t)(j0n + kr) * HD + kc * 8];
        vreg = *(const h8*)&Vb[(size_t)vr * NN + j0n + vc * 8];
      }

      // shared fragments (reused by both i-tiles)
      h8 ak[2][2], av[4];
#pragma unroll
      for (int ks = 0; ks < 2; ++ks)
#pragma unroll
        for (int jf = 0; jf < 2; ++jf)
          ak[ks][jf] = *(const h8*)(ksb + ((jf * 16 + p) << 7) + ((((ks << 2) | g) ^ (p & 7)) << 4));
#pragma unroll
      for (int ef = 0; ef < 4; ++ef)
        av[ef] = *(const h8*)(vsb + ((ef * 16 + p) << 6) + ((g ^ ((p >> 1) & 3)) << 4));

      // per i-tile: S'^T, exp, P write
#pragma unroll
      for (int it = 0; it < 2; ++it) {
        f4 s[2][2];
#pragma unroll
        for (int f = 0; f < 2; ++f)
#pragma unroll
          for (int jf = 0; jf < 2; ++jf) s[f][jf] = f4{-Mstar, -Mstar, -Mstar, -Mstar};
#pragma unroll
        for (int ks = 0; ks < 2; ++ks)
#pragma unroll
          for (int f = 0; f < 2; ++f)
#pragma unroll
            for (int jf = 0; jf < 2; ++jf) s[f][jf] = mfma16(ak[ks][jf], bq[it][f][ks], s[f][jf]);
#pragma unroll
        for (int f = 0; f < 2; ++f)
#pragma unroll
          for (int jf = 0; jf < 2; ++jf) {
            const f4 sv = s[f][jf];
            h2 lo = cvt_pk(exp2a(sv[0]), exp2a(sv[1]));
            h2 hi = cvt_pk(exp2a(sv[2]), exp2a(sv[3]));
            h4 pw; pw[0] = lo[0]; pw[1] = lo[1]; pw[2] = hi[0]; pw[3] = hi[1];
            *(h4*)(psb[it] + ((f * 16 + p) << 6) +
                   (((2 * jf + (g >> 1)) ^ ((p >> 1) & 3)) << 4) + ((g & 1) << 3)) = pw;
          }
      }
      // wave-private P: DS in-order per wave; insurance wait + scheduling fence
      asm volatile("s_waitcnt lgkmcnt(0)" ::: "memory");
      __builtin_amdgcn_sched_barrier(0);

      // PV for both i-tiles
#pragma unroll
      for (int it = 0; it < 2; ++it) {
        h8 bp[2];
#pragma unroll
        for (int f = 0; f < 2; ++f)
          bp[f] = *(const h8*)(psb[it] + ((f * 16 + p) << 6) + ((g ^ ((p >> 1) & 3)) << 4));
#pragma unroll
        for (int ef = 0; ef < 4; ++ef)
#pragma unroll
          for (int f = 0; f < 2; ++f) oacc[it][ef][f] = mfma16(av[ef], bp[f], oacc[it][ef][f]);
      }

      // write next tile into other buffer (no barrier needed: disjoint buf)
      if (jt + 1 < 32) {
        *(h8*)((char*)&Ks[cur ^ 1][0][0] + (kr << 7) + ((kc ^ (kr & 7)) << 4)) = kreg;
        *(h8*)((char*)&Vts[cur ^ 1][0][0] + (vr << 6) + ((vc ^ ((vr >> 1) & 3)) << 4)) = vreg;
      }
    }
  }

  // epilogue: lane (p,g): col i, rows e = ef*16+4g+r -> float4
#pragma unroll
  for (int it = 0; it < 2; ++it) {
#pragma unroll
    for (int f = 0; f < 2; ++f) {
      const int i = i0 + it * 128 + w * 32 + f * 16 + p;
#pragma unroll
      for (int ef = 0; ef < 4; ++ef) {
        float4 o4 = {oacc[it][ef][f][0], oacc[it][ef][f][1], oacc[it][ef][f][2], oacc[it][ef][f][3]};
        *(float4*)&Out[((size_t)b * NN + i) * EMB + h * HD + ef * 16 + 4 * g] = o4;
      }
    }
  }
}

extern "C" void kernel_launch(void* const* d_in, const int* in_sizes, int n_in,
                              void* d_out, int out_size, void* d_ws, size_t ws_size,
                              hipStream_t stream) {
  const float* X  = (const float*)d_in[0];
  const float* Wq = (const float*)d_in[1];
  const float* bq = (const float*)d_in[2];
  const float* Wk = (const float*)d_in[3];
  const float* bk = (const float*)d_in[4];
  const float* Wv = (const float*)d_in[5];
  const float* bv = (const float*)d_in[6];

  // workspace layout (~156.1 MB)
  char* ws = (char*)d_ws;
  _Float16* Qw = (_Float16*)(ws);                  // 50,331,648 B
  _Float16* Kw = (_Float16*)(ws + 50331648);       // 50,331,648 B
  _Float16* Vt = (_Float16*)(ws + 100663296);      // 50,331,648 B
  _Float16* Wt = (_Float16*)(ws + 150994944);      // 3 * 1,179,648 B
  float* Lg    = (float*)(ws + 154533888);         // 1,572,864 B
  float* MT    = (float*)(ws + 156106752);         // 12,288 B

  // transients inside d_out (overwritten by final f32 result at the end)
  _Float16* Xh   = (_Float16*)d_out;                        // 50,331,648 B
  _Float16* Vtmp = (_Float16*)((char*)d_out + 50331648);    // 50,331,648 B
  float* Out = (float*)d_out;

  k_cvt<<<dim3(6291456 / 256), 256, 0, stream>>>(X, Xh, 6291456);
  k_wt<<<dim3(12, 12, 3), 256, 0, stream>>>(Wq, Wk, Wv, Wt);
  k_proj<<<dim3(256, 6), 256, 0, stream>>>(Xh, Wt,           bq, Qw,   QSCALE);
  k_proj<<<dim3(256, 6), 256, 0, stream>>>(Xh, Wt + 589824,  bk, Kw,   1.0f);
  k_proj<<<dim3(256, 6), 256, 0, stream>>>(Xh, Wt + 1179648, bv, Vtmp, 1.0f);
  k_stats<<<dim3(8, 384), 256, 0, stream>>>(Qw, Kw, Lg, MT);
  k_vt<<<dim3(16, 384), 256, 0, stream>>>(Vtmp, Lg, Vt);
  k_out<<<dim3(8, 192), 256, 0, stream>>>(Qw, Kw, Vt, MT, Out);
}

// Round 8
// 397.332 us; speedup vs baseline: 1.4300x; 1.1250x over previous
//
#include <hip/hip_runtime.h>

#define EMB 768
#define NH 12
#define HD 64
#define BB 32
#define NN 1024
// log2(e)/sqrt(12): Q pre-scale so QK^T is in log2 domain
#define QSCALE 0.41647025f

typedef _Float16 h8 __attribute__((ext_vector_type(8)));
typedef _Float16 h4 __attribute__((ext_vector_type(4)));
typedef _Float16 h2 __attribute__((ext_vector_type(2)));
typedef float f4 __attribute__((ext_vector_type(4)));

static __device__ __forceinline__ f4 mfma16(h8 a, h8 b, f4 c) {
  return __builtin_amdgcn_mfma_f32_16x16x32_f16(a, b, c, 0, 0, 0);
}

static __device__ __forceinline__ h2 cvt_pk(float a, float b) {
  return __builtin_bit_cast(h2, __builtin_amdgcn_cvt_pkrtz(a, b));
}

static __device__ __forceinline__ float exp2a(float x) {
#if __has_builtin(__builtin_amdgcn_exp2f)
  return __builtin_amdgcn_exp2f(x);
#else
  float r;
  asm("v_exp_f32 %0, %1\n\ts_nop 1" : "=v"(r) : "v"(x));
  return r;
#endif
}

// async global->LDS, 16B per lane; LDS dest = wave-uniform base + lane*16
static __device__ __forceinline__ void gload16(const _Float16* g, _Float16* lds) {
  __builtin_amdgcn_global_load_lds(
      (const __attribute__((address_space(1))) void*)g,
      (__attribute__((address_space(3))) void*)lds, 16, 0, 0);
}

// ---------------- X f32 -> f16 ----------------
__global__ __launch_bounds__(256) void k_cvt(const float* __restrict__ X,
                                             _Float16* __restrict__ Xh, int n4) {
  int i = blockIdx.x * 256 + threadIdx.x;
  if (i >= n4) return;
  float4 v = ((const float4*)X)[i];
  h4 o = {(_Float16)v.x, (_Float16)v.y, (_Float16)v.z, (_Float16)v.w};
  ((h4*)Xh)[i] = o;
}

// ---------------- W (768x768 f32) -> W^T f16, all three ----------------
__global__ __launch_bounds__(256) void k_wt(const float* __restrict__ W0,
                                            const float* __restrict__ W1,
                                            const float* __restrict__ W2,
                                            _Float16* __restrict__ Wt) {
  const float* W = blockIdx.z == 0 ? W0 : (blockIdx.z == 1 ? W1 : W2);
  _Float16* dst = Wt + (size_t)blockIdx.z * EMB * EMB;
  __shared__ float tile[64][65];
  const int t = threadIdx.x;
  const int r0 = blockIdx.y * 64, c0 = blockIdx.x * 64;
  const int r = t >> 4, c4 = (t & 15) * 4;
#pragma unroll
  for (int i = 0; i < 4; ++i) {
    const float4 v = *(const float4*)&W[(size_t)(r0 + r + 16 * i) * EMB + c0 + c4];
    tile[r + 16 * i][c4 + 0] = v.x; tile[r + 16 * i][c4 + 1] = v.y;
    tile[r + 16 * i][c4 + 2] = v.z; tile[r + 16 * i][c4 + 3] = v.w;
  }
  __syncthreads();
  const int cc = t >> 2, rr = (t & 3) * 16;
#pragma unroll
  for (int half = 0; half < 2; ++half) {
    h8 o;
#pragma unroll
    for (int j = 0; j < 8; ++j) o[j] = (_Float16)tile[rr + half * 8 + j][cc];
    *(h8*)&dst[(size_t)(c0 + cc) * EMB + r0 + rr + half * 8] = o;
  }
}

// ---------------- fused QKV GEMM: [32768 x 768] @ [768 x 2304] ----------------
// m97-pattern: BK=64, double-buffered LDS via global_load_lds w16,
// linear LDS + inverse-swizzled global source + swizzled ds_read_b128 (rule #21).
__global__ __launch_bounds__(256) void k_projf(const _Float16* __restrict__ Xh,
                                               const _Float16* __restrict__ Wt,
                                               const float* __restrict__ bq,
                                               const float* __restrict__ bk,
                                               const float* __restrict__ bv,
                                               _Float16* __restrict__ Qw,
                                               _Float16* __restrict__ Kw,
                                               _Float16* __restrict__ Vtmp) {
  __shared__ _Float16 As[2][128 * 64];  // 16KB per buf
  __shared__ _Float16 Bs[2][128 * 64];
  const int t = threadIdx.x;
  const int w = t >> 6, l = t & 63;
  const int wm = w >> 1, wn = w & 1;
  const int p = l & 15, g = l >> 4;
  const int by = blockIdx.x;            // n-tile 0..17
  const int m0 = blockIdx.y * 128;      // m-tile 0..255
  const int n0 = by * 128;              // into flat Wt [2304][768]

  f4 acc[4][4];
#pragma unroll
  for (int mf = 0; mf < 4; ++mf)
#pragma unroll
    for (int nf = 0; nf < 4; ++nf) acc[mf][nf] = f4{0.f, 0.f, 0.f, 0.f};

  // staging geometry: lane l covers row (l>>3) of its 8-row segment, chunk (l&7)
  const int lrow = l >> 3, lch = (l & 7) ^ (l >> 3);  // inverse-swizzled source chunk

#define STAGE(buf, k0)                                                            \
  {                                                                               \
    _Float16* ab = &As[buf][0];                                                   \
    _Float16* bb = &Bs[buf][0];                                                   \
    _Pragma("unroll") for (int i = 0; i < 4; ++i) {                               \
      const int seg = (w << 2) | i;                                               \
      const int grow = (seg << 3) | lrow;                                         \
      gload16(Xh + (size_t)(m0 + grow) * EMB + (k0) + lch * 8, ab + seg * 512);   \
      gload16(Wt + (size_t)(n0 + grow) * EMB + (k0) + lch * 8, bb + seg * 512);   \
    }                                                                             \
  }

  STAGE(0, 0)
  __syncthreads();

  int cur = 0;
  for (int kt = 0; kt < 12; ++kt) {
    if (kt + 1 < 12) STAGE(cur ^ 1, (kt + 1) * 64)
    const char* asb = (const char*)&As[cur][0];
    const char* bsb = (const char*)&Bs[cur][0];
#pragma unroll
    for (int ks = 0; ks < 2; ++ks) {
      h8 af[4], bf[4];
#pragma unroll
      for (int mf = 0; mf < 4; ++mf)
        af[mf] = *(const h8*)(asb + ((wm * 64 + mf * 16 + p) << 7) +
                              ((((ks << 2) | g) ^ (p & 7)) << 4));
#pragma unroll
      for (int nf = 0; nf < 4; ++nf)
        bf[nf] = *(const h8*)(bsb + ((wn * 64 + nf * 16 + p) << 7) +
                              ((((ks << 2) | g) ^ (p & 7)) << 4));
#pragma unroll
      for (int mf = 0; mf < 4; ++mf)
#pragma unroll
        for (int nf = 0; nf < 4; ++nf) acc[mf][nf] = mfma16(af[mf], bf[nf], acc[mf][nf]);
    }
    __syncthreads();
    cur ^= 1;
  }
#undef STAGE

  // epilogue: z-select (tiles never straddle the 768 boundary: 768 % 128 == 0)
  const int z = by / 6;
  const int nl0 = (by % 6) * 128;
  const float* bias = z == 0 ? bq : (z == 1 ? bk : bv);
  _Float16* Outz = z == 0 ? Qw : (z == 1 ? Kw : Vtmp);
  const float scale = z == 0 ? QSCALE : 1.0f;
#pragma unroll
  for (int nf = 0; nf < 4; ++nf) {
    const int C = nl0 + wn * 64 + nf * 16 + p;
    const float bvv = bias[C];
    const int h = C >> 6, e = C & 63;
#pragma unroll
    for (int mf = 0; mf < 4; ++mf) {
#pragma unroll
      for (int r = 0; r < 4; ++r) {
        const int R = m0 + wm * 64 + mf * 16 + g * 4 + r;
        const int b = R >> 10, tok = R & 1023;
        Outz[((size_t)(b * NH + h) * NN + tok) * HD + e] = (_Float16)((acc[mf][nf][r] + bvv) * scale);
      }
    }
  }
}

// ---------------- column stats (log2, NO max): l~_j = sum_i 2^S'; MT = log2(max_j l~) ----------------
__global__ __launch_bounds__(256) void k_stats(const _Float16* __restrict__ Q,
                                               const _Float16* __restrict__ K,
                                               float* __restrict__ Lg, float* __restrict__ MT) {
  const int bh = blockIdx.x * 48 + (blockIdx.y >> 3);   // XCD-aware: bx = XCD
  const int jt = blockIdx.y & 7;
  const int j0 = jt * 128;
  __shared__ _Float16 Ks[128][64];  // 128B rows, XOR-swizzled chunks (mask 7)
  __shared__ _Float16 Qs[128][64];
  __shared__ float Lj[128];
  __shared__ float reds[2][128];
  __shared__ float MsSh;
  const _Float16* Qb = Q + (size_t)bh * NN * HD;
  const _Float16* Kb = K + (size_t)bh * NN * HD;
  const int t = threadIdx.x, w = t >> 6, l = t & 63;
  const int wi = w >> 1, wj = w & 1;
  const int p = l & 15, g = l >> 4;
  const int lr = t >> 3, tc = t & 7;  // staging: row lr(+32i), chunk tc
  char* ksb = (char*)&Ks[0][0];
  char* qsb = (char*)&Qs[0][0];
#pragma unroll
  for (int i = 0; i < 4; ++i)
    *(h8*)(ksb + ((lr + 32 * i) << 7) + ((tc ^ (lr & 7)) << 4)) =
        *(const h8*)&Kb[(size_t)(j0 + lr + 32 * i) * HD + tc * 8];
  if (t < 128) Lj[t] = 0.f;
  __syncthreads();

  for (int i0 = 0; i0 < NN; i0 += 128) {
#pragma unroll
    for (int i = 0; i < 4; ++i)
      *(h8*)(qsb + ((lr + 32 * i) << 7) + ((tc ^ (lr & 7)) << 4)) =
          *(const h8*)&Qb[(size_t)(i0 + lr + 32 * i) * HD + tc * 8];
    __syncthreads();
    f4 s[4][4];
#pragma unroll
    for (int mf = 0; mf < 4; ++mf)
#pragma unroll
      for (int nf = 0; nf < 4; ++nf) s[mf][nf] = f4{0.f, 0.f, 0.f, 0.f};
#pragma unroll
    for (int ks = 0; ks < 2; ++ks) {
      h8 af[4], bf[4];
#pragma unroll
      for (int mf = 0; mf < 4; ++mf)
        af[mf] = *(const h8*)(qsb + ((wi * 64 + mf * 16 + p) << 7) + ((((ks << 2) | g) ^ (p & 7)) << 4));
#pragma unroll
      for (int nf = 0; nf < 4; ++nf)
        bf[nf] = *(const h8*)(ksb + ((wj * 64 + nf * 16 + p) << 7) + ((((ks << 2) | g) ^ (p & 7)) << 4));
#pragma unroll
      for (int mf = 0; mf < 4; ++mf)
#pragma unroll
        for (int nf = 0; nf < 4; ++nf) s[mf][nf] = mfma16(af[mf], bf[nf], s[mf][nf]);
    }
    // direct f32 exp-sum over i (no max needed: |S'| bounded, f32 range ample)
#pragma unroll
    for (int nf = 0; nf < 4; ++nf) {
      float cs = 0.f;
#pragma unroll
      for (int mf = 0; mf < 4; ++mf)
#pragma unroll
        for (int r = 0; r < 4; ++r) cs += exp2a(s[mf][nf][r]);
      cs += __shfl_xor(cs, 16);
      cs += __shfl_xor(cs, 32);
      if (l < 16) reds[wi][wj * 64 + nf * 16 + l] = cs;
    }
    __syncthreads();
    if (t < 128) Lj[t] += reds[0][t] + reds[1][t];
    __syncthreads();
  }
  // tail: M* = log2(max_j l~_j)  (guarantees P = 2^(S'-M*) <= 1); Lg = l~ * 2^-M*
  if (w == 0) {
    float mv = fmaxf(Lj[l], Lj[l + 64]);
#pragma unroll
    for (int d = 32; d; d >>= 1) mv = fmaxf(mv, __shfl_xor(mv, d));
    if (l == 0) { MsSh = __log2f(mv); MT[bh * 8 + jt] = MsSh; }
  }
  __syncthreads();
  const float msc = exp2a(-MsSh);
  if (t < 128) Lg[(size_t)bh * NN + j0 + t] = Lj[t] * msc;
}

// ---------------- V [bh][j][e] -> Vt [bh][e][j] scaled by 1/Lg'[j] ----------------
__global__ __launch_bounds__(256) void k_vt(const _Float16* __restrict__ Vtmp,
                                            const float* __restrict__ Lg,
                                            _Float16* __restrict__ Vt) {
  const int bh = blockIdx.y, j0 = blockIdx.x * 64;
  __shared__ _Float16 tile[64][72];
  const _Float16* src = Vtmp + (size_t)bh * NN * HD;
  _Float16* dst = Vt + (size_t)bh * HD * NN;
  const int t = threadIdx.x;
  const int jr = t >> 3, e8 = (t & 7) * 8;
#pragma unroll
  for (int i = 0; i < 2; ++i) {
    const float inv = 1.0f / Lg[(size_t)bh * NN + j0 + jr + 32 * i];
    h8 v = *(const h8*)&src[(size_t)(j0 + jr + 32 * i) * HD + e8];
    h8 o;
#pragma unroll
    for (int j = 0; j < 8; ++j) o[j] = (_Float16)((float)v[j] * inv);
    *(h8*)&tile[jr + 32 * i][e8] = o;
  }
  __syncthreads();
  const int er = t >> 3, j8 = (t & 7) * 8;
#pragma unroll
  for (int i = 0; i < 2; ++i) {
    h8 o;
#pragma unroll
    for (int j = 0; j < 8; ++j) o[j] = tile[j8 + j][er + 32 * i];
    *(h8*)&dst[(size_t)(er + 32 * i) * NN + j0 + j8] = o;
  }
}

// ---------------- output: out = 2^(S' - M*) @ V'  (S^T trick; 2 i-tiles/block; unroll-4) ---------
__global__ __launch_bounds__(256) void k_out(const _Float16* __restrict__ Q,
                                             const _Float16* __restrict__ K,
                                             const _Float16* __restrict__ Vt,
                                             const float* __restrict__ MT,
                                             float* __restrict__ Out) {
  const int bh = blockIdx.x * 48 + (blockIdx.y >> 2);   // XCD-aware: bx = XCD
  const int i0 = (blockIdx.y & 3) * 256;
  const int b = bh / NH, h = bh % NH;
  __shared__ _Float16 Ks[2][32][64];      // [buf][j][e], 128B rows, swz mask 7
  __shared__ _Float16 Vts[2][64][32];     // [buf][e][j], 64B rows, swz (row>>1)&3
  __shared__ _Float16 Ps[4][2][32][32];   // [wave][it][i][j], wave-private
  const _Float16* Qb = Q + (size_t)bh * NN * HD;
  const _Float16* Kb = K + (size_t)bh * NN * HD;
  const _Float16* Vb = Vt + (size_t)bh * HD * NN;
  const int t = threadIdx.x, w = t >> 6, l = t & 63;
  const int p = l & 15, g = l >> 4;
  char* psb[2] = {(char*)&Ps[w][0][0][0], (char*)&Ps[w][1][0][0]};

  // Q B-frags for both i-tiles (col i = i0 + it*128 + w*32 + f*16 + p)
  h8 bq[2][2][2];
#pragma unroll
  for (int it = 0; it < 2; ++it)
#pragma unroll
    for (int f = 0; f < 2; ++f)
#pragma unroll
      for (int ks = 0; ks < 2; ++ks)
        bq[it][f][ks] = *(const h8*)&Qb[(size_t)(i0 + it * 128 + w * 32 + f * 16 + p) * HD + ks * 32 + g * 8];

  f4 oacc[2][4][2];  // [it][ef][if] -> D[e][i]
#pragma unroll
  for (int it = 0; it < 2; ++it)
#pragma unroll
    for (int ef = 0; ef < 4; ++ef)
#pragma unroll
      for (int f = 0; f < 2; ++f) oacc[it][ef][f] = f4{0.f, 0.f, 0.f, 0.f};

  // staging: K 32x64 (row kr, chunk kc), V 64x32 (row vr, chunk vc)
  const int kr = t >> 3, kc = t & 7;
  const int vr = t >> 2, vc = t & 3;

  h8 kreg = *(const h8*)&Kb[(size_t)kr * HD + kc * 8];
  h8 vreg = *(const h8*)&Vb[(size_t)vr * NN + vc * 8];
  *(h8*)((char*)&Ks[0][0][0] + (kr << 7) + ((kc ^ (kr & 7)) << 4)) = kreg;
  *(h8*)((char*)&Vts[0][0][0] + (vr << 6) + ((vc ^ ((vr >> 1) & 3)) << 4)) = vreg;

  for (int jt4 = 0; jt4 < 8; ++jt4) {
    const float Mstar = MT[bh * 8 + jt4];
#pragma unroll
    for (int u = 0; u < 4; ++u) {
      const int jt = jt4 * 4 + u;
      const int cur = u & 1;  // jt4*4 even -> jt&1 == u&1 (static)
      char* ksb = (char*)&Ks[cur][0][0];
      char* vsb = (char*)&Vts[cur][0][0];
      __syncthreads();  // staged buf[cur] visible; prev reads of buf[cur^1] done
      if (jt + 1 < 32) {
        const int j0n = (jt + 1) * 32;
        kreg = *(const h8*)&Kb[(size_t)(j0n + kr) * HD + kc * 8];
        vreg = *(const h8*)&Vb[(size_t)vr * NN + j0n + vc * 8];
      }

      // shared fragments (reused by both i-tiles)
      h8 ak[2][2], av[4];
#pragma unroll
      for (int ks = 0; ks < 2; ++ks)
#pragma unroll
        for (int jf = 0; jf < 2; ++jf)
          ak[ks][jf] = *(const h8*)(ksb + ((jf * 16 + p) << 7) + ((((ks << 2) | g) ^ (p & 7)) << 4));
#pragma unroll
      for (int ef = 0; ef < 4; ++ef)
        av[ef] = *(const h8*)(vsb + ((ef * 16 + p) << 6) + ((g ^ ((p >> 1) & 3)) << 4));

      // per i-tile: S'^T, exp, P write
#pragma unroll
      for (int it = 0; it < 2; ++it) {
        f4 s[2][2];
#pragma unroll
        for (int f = 0; f < 2; ++f)
#pragma unroll
          for (int jf = 0; jf < 2; ++jf) s[f][jf] = f4{-Mstar, -Mstar, -Mstar, -Mstar};
#pragma unroll
        for (int ks = 0; ks < 2; ++ks)
#pragma unroll
          for (int f = 0; f < 2; ++f)
#pragma unroll
            for (int jf = 0; jf < 2; ++jf) s[f][jf] = mfma16(ak[ks][jf], bq[it][f][ks], s[f][jf]);
#pragma unroll
        for (int f = 0; f < 2; ++f)
#pragma unroll
          for (int jf = 0; jf < 2; ++jf) {
            const f4 sv = s[f][jf];
            h2 lo = cvt_pk(exp2a(sv[0]), exp2a(sv[1]));
            h2 hi = cvt_pk(exp2a(sv[2]), exp2a(sv[3]));
            h4 pw; pw[0] = lo[0]; pw[1] = lo[1]; pw[2] = hi[0]; pw[3] = hi[1];
            *(h4*)(psb[it] + ((f * 16 + p) << 6) +
                   (((2 * jf + (g >> 1)) ^ ((p >> 1) & 3)) << 4) + ((g & 1) << 3)) = pw;
          }
      }
      // wave-private P: DS in-order per wave; insurance wait + scheduling fence
      asm volatile("s_waitcnt lgkmcnt(0)" ::: "memory");
      __builtin_amdgcn_sched_barrier(0);

      // PV for both i-tiles
#pragma unroll
      for (int it = 0; it < 2; ++it) {
        h8 bp[2];
#pragma unroll
        for (int f = 0; f < 2; ++f)
          bp[f] = *(const h8*)(psb[it] + ((f * 16 + p) << 6) + ((g ^ ((p >> 1) & 3)) << 4));
#pragma unroll
        for (int ef = 0; ef < 4; ++ef)
#pragma unroll
          for (int f = 0; f < 2; ++f) oacc[it][ef][f] = mfma16(av[ef], bp[f], oacc[it][ef][f]);
      }

      // write next tile into other buffer (no barrier needed: disjoint buf)
      if (jt + 1 < 32) {
        *(h8*)((char*)&Ks[cur ^ 1][0][0] + (kr << 7) + ((kc ^ (kr & 7)) << 4)) = kreg;
        *(h8*)((char*)&Vts[cur ^ 1][0][0] + (vr << 6) + ((vc ^ ((vr >> 1) & 3)) << 4)) = vreg;
      }
    }
  }

  // epilogue: lane (p,g): col i, rows e = ef*16+4g+r -> float4
#pragma unroll
  for (int it = 0; it < 2; ++it) {
#pragma unroll
    for (int f = 0; f < 2; ++f) {
      const int i = i0 + it * 128 + w * 32 + f * 16 + p;
#pragma unroll
      for (int ef = 0; ef < 4; ++ef) {
        float4 o4 = {oacc[it][ef][f][0], oacc[it][ef][f][1], oacc[it][ef][f][2], oacc[it][ef][f][3]};
        *(float4*)&Out[((size_t)b * NN + i) * EMB + h * HD + ef * 16 + 4 * g] = o4;
      }
    }
  }
}

extern "C" void kernel_launch(void* const* d_in, const int* in_sizes, int n_in,
                              void* d_out, int out_size, void* d_ws, size_t ws_size,
                              hipStream_t stream) {
  const float* X  = (const float*)d_in[0];
  const float* Wq = (const float*)d_in[1];
  const float* bq = (const float*)d_in[2];
  const float* Wk = (const float*)d_in[3];
  const float* bk = (const float*)d_in[4];
  const float* Wv = (const float*)d_in[5];
  const float* bv = (const float*)d_in[6];

  // workspace layout (~156.1 MB)
  char* ws = (char*)d_ws;
  _Float16* Qw = (_Float16*)(ws);                  // 50,331,648 B
  _Float16* Kw = (_Float16*)(ws + 50331648);       // 50,331,648 B
  _Float16* Vt = (_Float16*)(ws + 100663296);      // 50,331,648 B
  _Float16* Wt = (_Float16*)(ws + 150994944);      // 3 * 1,179,648 B
  float* Lg    = (float*)(ws + 154533888);         // 1,572,864 B
  float* MT    = (float*)(ws + 156106752);         // 12,288 B

  // transients inside d_out (overwritten by final f32 result at the end)
  _Float16* Xh   = (_Float16*)d_out;                        // 50,331,648 B
  _Float16* Vtmp = (_Float16*)((char*)d_out + 50331648);    // 50,331,648 B
  float* Out = (float*)d_out;

  k_cvt<<<dim3(6291456 / 256), 256, 0, stream>>>(X, Xh, 6291456);
  k_wt<<<dim3(12, 12, 3), 256, 0, stream>>>(Wq, Wk, Wv, Wt);
  k_projf<<<dim3(18, 256), 256, 0, stream>>>(Xh, Wt, bq, bk, bv, Qw, Kw, Vtmp);
  k_stats<<<dim3(8, 384), 256, 0, stream>>>(Qw, Kw, Lg, MT);
  k_vt<<<dim3(16, 384), 256, 0, stream>>>(Vtmp, Lg, Vt);
  k_out<<<dim3(8, 192), 256, 0, stream>>>(Qw, Kw, Vt, MT, Out);
}